// Round 20
// baseline (741.160 us; speedup 1.0000x reference)
//
#include <hip/hip_runtime.h>
#include <math.h>

#define DIVUP(a,b) (((a)+(b)-1)/(b))

typedef _Float16 f16x8 __attribute__((ext_vector_type(8)));
typedef _Float16 f16x4 __attribute__((ext_vector_type(4)));
typedef float    f32x4 __attribute__((ext_vector_type(4)));

// ---------------------------------------------------------------------------
// Implicit-GEMM conv, NHWC, single-fp16 MFMA: A fp16, W fp16, fp32 accum,
// fp16 OUTPUT. 8 MFMA / wave / K-step. BM=128, BN=64, BK=32. Geometry
// compile-time. BARRIER-FREE K-LOOP: both A and B load direct global->VGPR
// in frag layout (B panel <=74 KB, shared by all waves -> L1/L2-hot; 4 frag
// addrs per K-step = one base + 256B immediate offsets). Waves fully
// independent -> counted-vmcnt pipelines hide latency with 16 waves/CU.
// 2-deep named-register pipeline (aC/bC || aN/bN), ~80 VGPR live.
// LDS only for the stats reduction (one __syncthreads after the K-loop).
// XCD bijective swizzle (m204). POOL=1: quad-M + fused 2x2 maxpool.
// ---------------------------------------------------------------------------
template<int POOL, int C1, int HinP, int WinP, int Hout, int Wout, int Cout,
         int M, int NITER, int H2, int W2, int H2c, int W2c>
__global__ __launch_bounds__(256, 4) void conv_mfma(
    const _Float16* __restrict__ in, long inZstride,
    const _Float16* __restrict__ wt,
    _Float16* __restrict__ out, long outZstride, float2* __restrict__ part)
{
    __shared__ __align__(16) float2 red[64 * 17];   // stats reduction only

    // ---- bijective XCD swizzle (m204) ----
    int bx;
    {
        int n = gridDim.x, orig = blockIdx.x;
        int q = n >> 3, r = n & 7;
        int xcd = orig & 7, idx = orig >> 3;
        bx = (xcd < r ? xcd * (q + 1) : r * (q + 1) + (xcd - r) * q) + idx;
    }

    const int tid  = threadIdx.x;
    const int wv   = tid >> 6;
    const int ln15 = tid & 15;
    const int lhi  = (tid >> 4) & 3;

    const _Float16* ip = in + (size_t)blockIdx.z * inZstride;

    auto pixbase = [&](int mA) -> int {
        int nb, h, w; bool valid;
        if (POOL) {
            int r = mA & 3, quad = mA >> 2;
            const int cpi = H2c * W2c;
            nb = quad / cpi;
            int rem = quad - nb * cpi;
            int h2 = rem / W2c, w2 = rem - h2 * W2c;
            h = h2 * 2 + (r >> 1); w = w2 * 2 + (r & 1);
            valid = (mA < M) && (h < Hout) && (w < Wout);
        } else {
            const int HW = Hout * Wout;
            valid = mA < M;
            int mm = valid ? mA : 0;
            nb = mm / HW;
            int rem = mm - nb * HW;
            h = rem / Wout; w = rem - h * Wout;
        }
        if (!valid) { nb = 0; h = 0; w = 0; }
        if (C1) return ((nb * 256 + h) * 256 + w) * 4;
        return ((nb * HinP + h) * WinP + w) * 64;
    };
    auto rowvalid = [&](int mA) -> bool {
        if (POOL) {
            int r = mA & 3, quad = mA >> 2;
            const int cpi = H2c * W2c;
            int nb = quad / cpi;
            int rem = quad - nb * cpi;
            int h2 = rem / W2c, w2 = rem - h2 * W2c;
            int h = h2 * 2 + (r >> 1), w = w2 * 2 + (r & 1);
            return (mA < M) && (h < Hout) && (w < Wout);
        }
        return mA < M;
    };

    int abase[2];
#pragma unroll
    for (int q = 0; q < 2; ++q)
        abase[q] = pixbase(bx * 128 + wv * 32 + q * 16 + ln15);

    unsigned vmask = 0;
#pragma unroll
    for (int q = 0; q < 2; ++q)
#pragma unroll
        for (int r = 0; r < 4; ++r)
            vmask |= (unsigned)rowvalid(bx * 128 + wv * 32 + q * 16 + lhi * 4 + r)
                     << (q * 4 + r);

    const _Float16* wp = wt + (size_t)blockIdx.z * NITER * 2048;
    const _Float16* wlane = wp + (size_t)(lhi * 64 + ln15) * 8;   // + it*2048 + t*128

    auto loadA = [&](int it, f16x8 (&a)[2]) {
        int off;
        if (C1) off = it * 1024 + lhi * 8;
        else { int tap = it >> 1; int kh = tap / 3, kw = tap - 3 * kh;
               off = (kh * WinP + kw) * 64 + (it & 1) * 32 + lhi * 8; }
#pragma unroll
        for (int q = 0; q < 2; ++q)
            a[q] = *(const f16x8*)(ip + abase[q] + off);
    };
    auto loadB = [&](int it, f16x8 (&b)[4]) {
        const _Float16* base = wlane + (size_t)it * 2048;
#pragma unroll
        for (int t = 0; t < 4; ++t)
            b[t] = *(const f16x8*)(base + t * 128);
    };

    f32x4 acc[2][4] = {};
    f16x8 aC[2], bC[4], aN[2], bN[4];

    loadA(0, aC); loadB(0, bC);
    for (int it = 0; it < NITER; it += 2) {
        if (it + 1 < NITER) { loadA(it + 1, aN); loadB(it + 1, bN); }
#pragma unroll
        for (int t = 0; t < 4; ++t)
#pragma unroll
            for (int q = 0; q < 2; ++q)
                acc[q][t] = __builtin_amdgcn_mfma_f32_16x16x32_f16(aC[q], bC[t], acc[q][t], 0, 0, 0);
        if (it + 2 < NITER) { loadA(it + 2, aC); loadB(it + 2, bC); }
        if (it + 1 < NITER) {
#pragma unroll
            for (int t = 0; t < 4; ++t)
#pragma unroll
                for (int q = 0; q < 2; ++q)
                    acc[q][t] = __builtin_amdgcn_mfma_f32_16x16x32_f16(aN[q], bN[t], acc[q][t], 0, 0, 0);
        }
    }

    // ---- per-block per-channel (sum,sumsq) partials (masked rows) ----
#pragma unroll
    for (int t = 0; t < 4; ++t) {
        float s = 0.f, s2 = 0.f;
#pragma unroll
        for (int q = 0; q < 2; ++q)
#pragma unroll
            for (int r = 0; r < 4; ++r) {
                float v = ((vmask >> (q * 4 + r)) & 1u) ? acc[q][t][r] : 0.f;
                s += v; s2 += v * v;
            }
        red[(ln15 + 16 * t) * 17 + (wv * 4 + lhi)] = make_float2(s, s2);
    }
    __syncthreads();
    if (tid < 64) {
        float s = 0.f, s2 = 0.f;
#pragma unroll
        for (int q = 0; q < 16; ++q) { float2 v = red[tid * 17 + q]; s += v.x; s2 += v.y; }
        part[((size_t)blockIdx.z * 64 + tid) * gridDim.x + bx] = make_float2(s, s2);
    }

    // ---- NHWC fp16 output ----
    _Float16* zout = out + (size_t)blockIdx.z * outZstride;
#pragma unroll
    for (int q = 0; q < 2; ++q) {
        const int mbase = bx * 128 + wv * 32 + q * 16 + lhi * 4;
        if (POOL) {
            if (mbase < M) {
                int quad = mbase >> 2;
                const int cpi = H2c * W2c;
                int nb2  = quad / cpi;
                int rem  = quad - nb2 * cpi;
                int h2 = rem / W2c, w2 = rem - h2 * W2c;
                if (h2 < H2 && w2 < W2) {
                    _Float16* op = zout + ((size_t)(nb2 * H2 + h2) * W2 + w2) * Cout;
#pragma unroll
                    for (int t = 0; t < 4; ++t) {
                        int n = ln15 + 16 * t;
                        if (n < Cout) {
                            float mx = fmaxf(fmaxf(acc[q][t][0], acc[q][t][1]),
                                             fmaxf(acc[q][t][2], acc[q][t][3]));
                            op[n] = (_Float16)mx;
                        }
                    }
                }
            }
        } else {
#pragma unroll
            for (int r = 0; r < 4; ++r) {
                int m = mbase + r;
                if (m < M) {
                    _Float16* op = zout + (size_t)m * Cout;
#pragma unroll
                    for (int t = 0; t < 4; ++t) {
                        int n = ln15 + 16 * t;
                        if (n < Cout) op[n] = (_Float16)acc[q][t][r];
                    }
                }
            }
        }
    }
}

// partials -> (mean, rsqrt(var+eps)) per (z,channel)
__global__ __launch_bounds__(256) void bn_finalize(const float2* __restrict__ part,
                                                   int nblkx, double Ninv,
                                                   float2* __restrict__ stats)
{
    __shared__ double sh[512];
    const int zc = blockIdx.x, tid = threadIdx.x;
    const float2* p = part + (size_t)zc * nblkx;
    double s = 0, s2 = 0;
    for (int i = tid; i < nblkx; i += 256) { s += p[i].x; s2 += p[i].y; }
    sh[tid] = s; sh[256 + tid] = s2;
    __syncthreads();
    for (int st = 128; st > 0; st >>= 1) {
        if (tid < st) { sh[tid] += sh[tid + st]; sh[256 + tid] += sh[256 + tid + st]; }
        __syncthreads();
    }
    if (tid == 0) {
        float mean = (float)(sh[0] * Ninv);
        float var  = (float)(sh[256] * Ninv - (double)mean * (double)mean);
        if (var < 0.f) var = 0.f;
        stats[zc] = make_float2(mean, rsqrtf(var + 1e-5f));
    }
}

// raw NHWC fp16 + stats -> padded NHWC fp16 with zero border.
__global__ void bn_split(const _Float16* __restrict__ raw, const float2* __restrict__ stats,
                         _Float16* __restrict__ outF, int H, int W, int total)
{
    int idx = blockIdx.x * 256 + threadIdx.x;
    if (idx >= total) return;
    const int Hp = H + 2, Wp = W + 2;
    int c4 = idx & 15;
    int t  = idx >> 4;
    int wp = t % Wp; t /= Wp;
    int hp = t % Hp; int img = t / Hp;
    size_t o = (((size_t)img * Hp + hp) * Wp + wp) * 64 + c4 * 4;
    f16x4 hi;
    if (hp == 0 || hp == Hp - 1 || wp == 0 || wp == Wp - 1) {
#pragma unroll
        for (int j = 0; j < 4; ++j) hi[j] = (_Float16)0.f;
    } else {
        f16x4 v = *(const f16x4*)(raw + (((size_t)img * H + (hp - 1)) * W + (wp - 1)) * 64 + c4 * 4);
        const float2* st = stats + (img >> 4) * 64 + c4 * 4;
#pragma unroll
        for (int j = 0; j < 4; ++j) {
            float2 s = st[j];
            hi[j] = (_Float16)fmaxf(((float)v[j] - s.x) * s.y, 0.f);
        }
    }
    *(f16x4*)(outF + o) = hi;
}

// pooled fp16 [P][16][H][W][64] + stats + d -> XB padded fp16
__global__ void mix_split(const _Float16* __restrict__ pooled, const float2* __restrict__ stats,
                          const float* __restrict__ d, _Float16* __restrict__ outF,
                          int H, int W, int P, long strideP, int total)
{
    int idx = blockIdx.x * 256 + threadIdx.x;
    if (idx >= total) return;
    const int Hp = H + 2, Wp = W + 2;
    int c4 = idx & 15;
    int t  = idx >> 4;
    int wp = t % Wp; t /= Wp;
    int hp = t % Hp; t /= Hp;
    int n  = t & 15;
    int cc = t >> 4;
    size_t o = (((size_t)(cc * 16 + n) * Hp + hp) * Wp + wp) * 64 + c4 * 4;
    f16x4 hi;
    if (hp == 0 || hp == Hp - 1 || wp == 0 || wp == Wp - 1) {
#pragma unroll
        for (int j = 0; j < 4; ++j) hi[j] = (_Float16)0.f;
    } else {
        float a[4] = {0.f, 0.f, 0.f, 0.f};
        const _Float16* pb = pooled + (((size_t)n * H + (hp - 1)) * W + (wp - 1)) * 64 + c4 * 4;
        for (int p = 0; p < P; ++p) {
            f16x4 v = *(const f16x4*)(pb + (size_t)p * strideP);
            const float2* st = stats + p * 64 + c4 * 4;
            float dc = d[cc * P + p];
#pragma unroll
            for (int j = 0; j < 4; ++j) {
                float2 s = st[j];
                a[j] = fmaf(dc, fmaxf(((float)v[j] - s.x) * s.y, 0.f), a[j]);
            }
        }
#pragma unroll
        for (int j = 0; j < 4; ++j) hi[j] = (_Float16)a[j];
    }
    *(f16x4*)(outF + o) = hi;
}

// L3 mix: pooled fp16 [16][16][7][7][32] -> XB3 fp32 [40][16][7][7][32]
__global__ void mix_last(const _Float16* __restrict__ pooled, const float2* __restrict__ stats,
                         const float* __restrict__ d, float* __restrict__ out, int total)
{
    int idx = blockIdx.x * 256 + threadIdx.x;
    if (idx >= total) return;
    int c  = idx & 31;
    int t  = idx >> 5;
    int hw = t % 49; t /= 49;
    int n  = t & 15;
    int a  = t >> 4;
    float acc = 0.f;
    const _Float16* pb = pooled + ((size_t)n * 49 + hw) * 32 + c;
    for (int p = 0; p < 16; ++p) {
        float2 s = stats[p * 64 + c];
        acc = fmaf(d[a * 16 + p], fmaxf(((float)pb[(size_t)p * 25088] - s.x) * s.y, 0.f), acc);
    }
    out[idx] = acc;
}

// x NCHW [16][3][256][256] -> packed NHWC4 fp16 [16][256][256][4]
__global__ void prep_x(const float* __restrict__ x, _Float16* __restrict__ xF)
{
    int idx = blockIdx.x * 256 + threadIdx.x;   // 16*65536
    if (idx >= 16 * 65536) return;
    int n = idx >> 16, hw = idx & 65535;
    f16x4 hi;
#pragma unroll
    for (int ci = 0; ci < 3; ++ci)
        hi[ci] = (_Float16)x[((size_t)n * 3 + ci) * 65536 + hw];
    hi[3] = (_Float16)0.f;
    *(f16x4*)(xF + (size_t)idx * 4) = hi;
}

// conv1 weights [64][3][7][7] -> fp16 panel [28 kblk][64][8], k=kh*32+kw*4+ci
__global__ void wtrans1(const float* __restrict__ w, _Float16* __restrict__ wt)
{
    int i = blockIdx.x * 256 + threadIdx.x;
    if (i >= 28 * 512) return;
    int j = i & 7, n = (i >> 3) & 63, kb = i >> 9;
    int k = kb * 8 + j;
    int kh = k >> 5, r = k & 31, kw = r >> 2, ci = r & 3;
    float v = (kw < 7 && ci < 3) ? w[((n * 3 + ci) * 7 + kh) * 7 + kw] : 0.f;
    wt[i] = (_Float16)v;
}

// 3x3 weights [P][Cout][64][3][3] -> fp16 panels [p][72 kblk][64][8]
__global__ void wtrans3(const float* __restrict__ w, _Float16* __restrict__ wt,
                        int P, int Cout)
{
    int total = P * 72 * 512;
    for (int i = blockIdx.x * 256 + threadIdx.x; i < total; i += gridDim.x * 256) {
        int j = i & 7, n = (i >> 3) & 63, kb = (i >> 9) % 72, p = (i >> 9) / 72;
        int k = kb * 8 + j;
        int ci = k & 63, tap = k >> 6, kh = tap / 3, kw = tap - 3 * kh;
        float v = (n < Cout) ? w[(((size_t)(p * Cout + n)) * 64 + ci) * 9 + kh * 3 + kw] : 0.f;
        wt[i] = (_Float16)v;
    }
}

// d = softmax_p( log(softmax_p(br*2)) / t ) for all 4 layers
__global__ void dcalc(const float* __restrict__ br0, const float* __restrict__ br1,
                      const float* __restrict__ br2, const float* __restrict__ br3,
                      const void* __restrict__ tptr, float* __restrict__ D)
{
    const int L = blockIdx.x;
    const float* br; int C, P, off;
    if      (L == 0) { br = br0; C = 4;  P = 2;  off = 0;   }
    else if (L == 1) { br = br1; C = 8;  P = 4;  off = 8;   }
    else if (L == 2) { br = br2; C = 16; P = 8;  off = 40;  }
    else             { br = br3; C = 40; P = 16; off = 168; }
    int ti = *(const int*)tptr;
    float t = (ti > 0 && ti < 1000000) ? (float)ti : *(const float*)tptr;
    const int c = threadIdx.x;
    if (c >= C) return;
    float u[16];
    float mx = -1e30f;
#pragma unroll
    for (int p = 0; p < 16; ++p) if (p < P) { u[p] = br[c * P + p] * 2.0f; mx = fmaxf(mx, u[p]); }
    float se = 0.f;
#pragma unroll
    for (int p = 0; p < 16; ++p) if (p < P) se += expf(u[p] - mx);
    float lse = mx + logf(se);
    float mx2 = -1e30f;
#pragma unroll
    for (int p = 0; p < 16; ++p) if (p < P) { u[p] = (u[p] - lse) / t; mx2 = fmaxf(mx2, u[p]); }
    float se2 = 0.f;
#pragma unroll
    for (int p = 0; p < 16; ++p) if (p < P) { u[p] = expf(u[p] - mx2); se2 += u[p]; }
#pragma unroll
    for (int p = 0; p < 16; ++p) if (p < P) D[off + c * P + p] = u[p] / se2;
}

// h1[a,b,i] = relu( sum_f f[a,b,f]*fw1[a,f,i] + fb1[a,i] ); f stored (h,w,c),
// fw1 indexed (c,h,w)
__global__ __launch_bounds__(128) void fc1_k(const float* __restrict__ f,
                                             const float* __restrict__ w1,
                                             const float* __restrict__ b1,
                                             float* __restrict__ h1)
{
    const int a = blockIdx.x >> 4;
    const int b = blockIdx.x & 15;
    const int i = threadIdx.x;
    const float* fv = f + ((size_t)a * 16 + b) * 1568;
    const float* wv = w1 + (size_t)a * 1568 * 128 + i;
    float acc = b1[a * 128 + i];
    for (int hw = 0; hw < 49; ++hw)
        for (int c = 0; c < 32; ++c)
            acc = fmaf(fv[hw * 32 + c], wv[(size_t)(c * 49 + hw) * 128], acc);
    h1[((size_t)a * 16 + b) * 128 + i] = fmaxf(acc, 0.f);
}

__global__ __launch_bounds__(128) void fc23_k(const float* __restrict__ h1,
                                              const float* __restrict__ w2,
                                              const float* __restrict__ b2,
                                              const float* __restrict__ w3,
                                              const float* __restrict__ b3,
                                              float* __restrict__ out)
{
    __shared__ float sh1[16][128];
    __shared__ float sh2[16][128];
    const int a = blockIdx.x;
    const int i = threadIdx.x;
    for (int b = 0; b < 16; ++b) sh1[b][i] = h1[((size_t)a * 16 + b) * 128 + i];
    __syncthreads();
    float acc[16];
#pragma unroll
    for (int b = 0; b < 16; ++b) acc[b] = b2[a * 128 + i];
    for (int ff = 0; ff < 128; ++ff) {
        float wv = w2[((size_t)a * 128 + ff) * 128 + i];
#pragma unroll
        for (int b = 0; b < 16; ++b) acc[b] = fmaf(sh1[b][ff], wv, acc[b]);
    }
    for (int b = 0; b < 16; ++b) sh2[b][i] = fmaxf(acc[b], 0.f);
    __syncthreads();
    if (i < 16) {
        float o = b3[a];
        for (int ff = 0; ff < 128; ++ff) o = fmaf(sh2[i][ff], w3[a * 128 + ff], o);
        out[i * 40 + a] = o;
    }
}

extern "C" void kernel_launch(void* const* d_in, const int* in_sizes, int n_in,
                              void* d_out, int out_size, void* d_ws, size_t ws_size,
                              hipStream_t stream)
{
    (void)in_sizes; (void)n_in;

    const float* x   = (const float*)d_in[0];
    const float* w10 = (const float*)d_in[1];
    const float* wa[4] = {(const float*)d_in[3],  (const float*)d_in[7],
                          (const float*)d_in[11], (const float*)d_in[15]};
    const float* wb[4] = {(const float*)d_in[5],  (const float*)d_in[9],
                          (const float*)d_in[13], (const float*)d_in[17]};
    const float* br[4] = {(const float*)d_in[19], (const float*)d_in[20],
                          (const float*)d_in[21], (const float*)d_in[22]};
    const float* fw1 = (const float*)d_in[23];
    const float* fb1 = (const float*)d_in[24];
    const float* fw2 = (const float*)d_in[25];
    const float* fb2 = (const float*)d_in[26];
    const float* fw3 = (const float*)d_in[27];
    const float* fb3 = (const float*)d_in[28];
    float* out = (float*)d_out;

    const int Pl[4]  = {2, 4, 8, 16};
    const int CBs[4] = {64, 64, 64, 32};

    // ---- workspace arenas (f32 units); total ~47.0M f32 = 188 MB ----
    const size_t NEED = 47000000ull * 4ull;
    if (ws_size < NEED) {
        hipMemsetAsync(d_out, 0, (size_t)out_size * sizeof(float), stream);
        return;
    }
    float* ws = (float*)d_ws;
    size_t o = 0;
    _Float16* WT1 = (_Float16*)(ws + o); o += 7168;
    _Float16 *WTA[4], *WTB[4];
    for (int L = 0; L < 4; ++L) {
        WTA[L] = (_Float16*)(ws + o); o += (size_t)Pl[L] * 18432;
        WTB[L] = (_Float16*)(ws + o); o += (size_t)Pl[L] * 18432;
    }
    float*  D     = ws + o; o += 1024;
    float2* STATS = (float2*)(ws + o); o += 4352;
    float2* STATS_C1 = STATS;
    float2* STATS_A  = STATS + 64;     // up to 128 entries (z-batched L0)
    float2* STATS_B  = STATS + 1088;
    float*  H1 = ws + o; o += 81920;
    float*  A6 = ws + o; o += 524288;      // conv partials
    float*  A5 = ws + o; o += 4000000;     // pooled fp16 / conv1 partials
    float*  A4 = ws + o; o += 16000000;    // raw conv outputs fp16 NHWC
    float*  A3 = ws + o; o += 16600000;    // fp16 split buf / xc
    float*  A2 = ws + o; o += 8400000;     // fp16 Y / XB chain / XB3 fp32

    float2* PART   = (float2*)A6;
    float2* PARTC1 = (float2*)A5;          // conv1: 64x7813 float2 fits 4M f32
    _Float16* xcF = (_Float16*)A3;
    _Float16* A2F = (_Float16*)A2;
    _Float16* A3F = (_Float16*)A3;
    _Float16* A4F = (_Float16*)A4;
    _Float16* A5F = (_Float16*)A5;

    // ---- weights + mix coefficients + conv1 input prep ----
    prep_x<<<4096, 256, 0, stream>>>(x, xcF);
    wtrans1<<<56, 256, 0, stream>>>(w10, WT1);
    for (int L = 0; L < 4; ++L) {
        int tA = Pl[L] * 72 * 512;
        wtrans3<<<DIVUP(tA, 256), 256, 0, stream>>>(wa[L], WTA[L], Pl[L], 64);
        wtrans3<<<DIVUP(tA, 256), 256, 0, stream>>>(wb[L], WTB[L], Pl[L], CBs[L]);
    }
    dcalc<<<4, 64, 0, stream>>>(br[0], br[1], br[2], br[3], d_in[29], D);

    // ---- conv1: xc -> pooled raw fp16 A4 [16,125,125,64] + stats ----
    conv_mfma<1, 1, 256, 256, 250, 250, 64, 1000000, 7, 125, 125, 125, 125>
        <<<dim3(7813, 1, 1), 256, 0, stream>>>(xcF, 0, WT1, A4F, 0, PARTC1);
    bn_finalize<<<64, 256, 0, stream>>>(PARTC1, 7813, 1.0 / 1000000.0, STATS_C1);
    bn_split<<<DIVUP(16 * 127 * 127 * 16, 256), 256, 0, stream>>>(
        A4F, STATS_C1, A2F, 125, 125, 16 * 127 * 127 * 16);

    // ---- layer 0: both parents z-batched (shared input Y) ----
    conv_mfma<0, 0, 127, 127, 125, 125, 64, 250000, 18, 0, 0, 1, 1>
        <<<dim3(1954, 1, 2), 256, 0, stream>>>(
            A2F, 0, WTA[0], A4F, 16000000, PART);
    bn_finalize<<<128, 256, 0, stream>>>(PART, 1954, 1.0 / 250000.0, STATS_A);
    bn_split<<<DIVUP(2 * 16 * 127 * 127 * 16, 256), 256, 0, stream>>>(
        A4F, STATS_A, A3F, 125, 125, 2 * 16 * 127 * 127 * 16);
    conv_mfma<1, 0, 127, 127, 125, 125, 64, 254016, 18, 62, 62, 63, 63>
        <<<dim3(1985, 1, 2), 256, 0, stream>>>(
            A3F, 16516096, WTB[0], A5F, 3936256, PART);
    bn_finalize<<<128, 256, 0, stream>>>(PART, 1985, 1.0 / 250000.0, STATS_B);
    mix_split<<<DIVUP(4 * 16 * 64 * 64 * 16, 256), 256, 0, stream>>>(
        A5F, STATS_B, D + 0, A2F, 62, 62, 2, 3936256, 4 * 16 * 64 * 64 * 16);

    // ---- layer 1 (z=4) ----
    conv_mfma<0, 0, 64, 64, 62, 62, 64, 61504, 18, 0, 0, 1, 1>
        <<<dim3(481, 1, 4), 256, 0, stream>>>(
            A2F, 4194304, WTA[1], A4F, 3936256, PART);
    bn_finalize<<<256, 256, 0, stream>>>(PART, 481, 1.0 / 61504.0, STATS_A);
    bn_split<<<DIVUP(64 * 64 * 64 * 16, 256), 256, 0, stream>>>(
        A4F, STATS_A, A3F, 62, 62, 64 * 64 * 64 * 16);
    conv_mfma<1, 0, 64, 64, 62, 62, 64, 61504, 18, 31, 31, 31, 31>
        <<<dim3(481, 1, 4), 256, 0, stream>>>(
            A3F, 4194304, WTB[1], A5F, 984064, PART);
    bn_finalize<<<256, 256, 0, stream>>>(PART, 481, 1.0 / 61504.0, STATS_B);
    mix_split<<<DIVUP(8 * 16 * 33 * 33 * 16, 256), 256, 0, stream>>>(
        A5F, STATS_B, D + 8, A2F, 31, 31, 4, 984064, 8 * 16 * 33 * 33 * 16);

    // ---- layer 2 (z=8) ----
    conv_mfma<0, 0, 33, 33, 31, 31, 64, 15376, 18, 0, 0, 1, 1>
        <<<dim3(121, 1, 8), 256, 0, stream>>>(
            A2F, 1115136, WTA[2], A4F, 984064, PART);
    bn_finalize<<<512, 256, 0, stream>>>(PART, 121, 1.0 / 15376.0, STATS_A);
    bn_split<<<DIVUP(128 * 33 * 33 * 16, 256), 256, 0, stream>>>(
        A4F, STATS_A, A3F, 31, 31, 128 * 33 * 33 * 16);
    conv_mfma<1, 0, 33, 33, 31, 31, 64, 16384, 18, 15, 15, 16, 16>
        <<<dim3(128, 1, 8), 256, 0, stream>>>(
            A3F, 1115136, WTB[2], A5F, 230400, PART);
    bn_finalize<<<512, 256, 0, stream>>>(PART, 128, 1.0 / 15376.0, STATS_B);
    mix_split<<<DIVUP(16 * 16 * 17 * 17 * 16, 256), 256, 0, stream>>>(
        A5F, STATS_B, D + 40, A2F, 15, 15, 8, 230400, 16 * 16 * 17 * 17 * 16);

    // ---- layer 3 (z=16) ----
    conv_mfma<0, 0, 17, 17, 15, 15, 64, 3600, 18, 0, 0, 1, 1>
        <<<dim3(29, 1, 16), 256, 0, stream>>>(
            A2F, 295936, WTA[3], A4F, 230400, PART);
    bn_finalize<<<1024, 256, 0, stream>>>(PART, 29, 1.0 / 3600.0, STATS_A);
    bn_split<<<DIVUP(256 * 17 * 17 * 16, 256), 256, 0, stream>>>(
        A4F, STATS_A, A3F, 15, 15, 256 * 17 * 17 * 16);
    conv_mfma<1, 0, 17, 17, 15, 15, 32, 4096, 18, 7, 7, 8, 8>
        <<<dim3(32, 1, 16), 256, 0, stream>>>(
            A3F, 295936, WTB[3], A5F, 25088, PART);
    bn_finalize<<<1024, 256, 0, stream>>>(PART, 32, 1.0 / 3600.0, STATS_B);
    mix_last<<<DIVUP(40 * 16 * 49 * 32, 256), 256, 0, stream>>>(
        A5F, STATS_B, D + 168, A2, 40 * 16 * 49 * 32);

    // ---- FC heads ----
    fc1_k<<<640, 128, 0, stream>>>(A2, fw1, fb1, H1);
    fc23_k<<<40, 128, 0, stream>>>(H1, fw2, fb2, fw3, fb3, out);
}

// Round 21
// 688.285 us; speedup vs baseline: 1.0768x; 1.0768x over previous
//
#include <hip/hip_runtime.h>
#include <math.h>

#define DIVUP(a,b) (((a)+(b)-1)/(b))

typedef _Float16 f16x8 __attribute__((ext_vector_type(8)));
typedef _Float16 f16x4 __attribute__((ext_vector_type(4)));
typedef float    f32x4 __attribute__((ext_vector_type(4)));

// K-loop barrier: LDS-only wait + raw barrier (vmcnt stays in flight).
#define LBAR() do { asm volatile("s_waitcnt lgkmcnt(0)" ::: "memory"); \
                    __builtin_amdgcn_s_barrier(); } while (0)

// ---------------------------------------------------------------------------
// Implicit-GEMM conv, NHWC, single-fp16 MFMA: A fp16, W fp16, fp32 accum,
// fp16 OUTPUT. 8 MFMA / wave / K-step. BM=128, BN=64, BK=32. Geometry
// compile-time (R19 structure = best measured, 636 us).
// A: direct global->VGPR frag layout, 3-deep register pipeline, unconditional
//    loads. B: LDS [64][40] double-buffered, lgkm-only barrier per K-step.
// launch_bounds(256,6): VGPR budget ~85 >= measured need 48 -> no spill,
// 6 blocks/CU (24 waves) vs R19's 4 -> 1.5x TLP for the latency-bound loop.
// XCD bijective swizzle (m204). POOL=1: quad-M + fused 2x2 maxpool.
// ---------------------------------------------------------------------------
template<int POOL, int C1, int HinP, int WinP, int Hout, int Wout, int Cout,
         int M, int NITER, int H2, int W2, int H2c, int W2c>
__global__ __launch_bounds__(256, 6) void conv_mfma(
    const _Float16* __restrict__ in, long inZstride,
    const _Float16* __restrict__ wt,
    _Float16* __restrict__ out, long outZstride, float2* __restrict__ part)
{
    __shared__ __align__(16) char smem[10240];   // B dbuf: 2 x 5120; red overlay
    float2* red = (float2*)smem;                 // [64][17] after K-loop

    // ---- bijective XCD swizzle (m204) ----
    int bx;
    {
        int n = gridDim.x, orig = blockIdx.x;
        int q = n >> 3, r = n & 7;
        int xcd = orig & 7, idx = orig >> 3;
        bx = (xcd < r ? xcd * (q + 1) : r * (q + 1) + (xcd - r) * q) + idx;
    }

    const int tid  = threadIdx.x;
    const int wv   = tid >> 6;
    const int ln15 = tid & 15;
    const int lhi  = (tid >> 4) & 3;
    const int sn   = tid & 63;        // B stage: n row this thread stages
    const int skb  = tid >> 6;        // B stage: kb slot
    const int sdst = sn * 40 + skb * 8;

    const _Float16* ip = in + (size_t)blockIdx.z * inZstride;

    auto pixbase = [&](int mA) -> int {
        int nb, h, w; bool valid;
        if (POOL) {
            int r = mA & 3, quad = mA >> 2;
            const int cpi = H2c * W2c;
            nb = quad / cpi;
            int rem = quad - nb * cpi;
            int h2 = rem / W2c, w2 = rem - h2 * W2c;
            h = h2 * 2 + (r >> 1); w = w2 * 2 + (r & 1);
            valid = (mA < M) && (h < Hout) && (w < Wout);
        } else {
            const int HW = Hout * Wout;
            valid = mA < M;
            int mm = valid ? mA : 0;
            nb = mm / HW;
            int rem = mm - nb * HW;
            h = rem / Wout; w = rem - h * Wout;
        }
        if (!valid) { nb = 0; h = 0; w = 0; }
        if (C1) return ((nb * 256 + h) * 256 + w) * 4;
        return ((nb * HinP + h) * WinP + w) * 64;
    };
    auto rowvalid = [&](int mA) -> bool {
        if (POOL) {
            int r = mA & 3, quad = mA >> 2;
            const int cpi = H2c * W2c;
            int nb = quad / cpi;
            int rem = quad - nb * cpi;
            int h2 = rem / W2c, w2 = rem - h2 * W2c;
            int h = h2 * 2 + (r >> 1), w = w2 * 2 + (r & 1);
            return (mA < M) && (h < Hout) && (w < Wout);
        }
        return mA < M;
    };

    int abase[2];
#pragma unroll
    for (int q = 0; q < 2; ++q)
        abase[q] = pixbase(bx * 128 + wv * 32 + q * 16 + ln15);

    unsigned vmask = 0;
#pragma unroll
    for (int q = 0; q < 2; ++q)
#pragma unroll
        for (int r = 0; r < 4; ++r)
            vmask |= (unsigned)rowvalid(bx * 128 + wv * 32 + q * 16 + lhi * 4 + r)
                     << (q * 4 + r);

    const _Float16* wp = wt + (size_t)blockIdx.z * NITER * 2048;

    auto loadA = [&](int it, f16x8 (&a)[2]) {
        int off;
        if (C1) off = it * 1024 + lhi * 8;
        else { int tap = it >> 1; int kh = tap / 3, kw = tap - 3 * kh;
               off = (kh * WinP + kw) * 64 + (it & 1) * 32 + lhi * 8; }
#pragma unroll
        for (int q = 0; q < 2; ++q)
            a[q] = *(const f16x8*)(ip + abase[q] + off);
    };

    f32x4 acc[2][4] = {};
    f16x8 a0[2], a1[2], a2[2];
    f16x8 sb;

    // ---- prologue: buf0 <- B(0); a0/a1/a2 <- A(0..2); sb <- B(1) ----
    {
        f16x8 h = *(const f16x8*)(wp + (size_t)(skb * 64 + sn) * 8);
        *(f16x8*)((_Float16*)smem + sdst) = h;
        loadA(0, a0);
        if (NITER > 1) {
            loadA(1, a1);
            sb = *(const f16x8*)(wp + (size_t)((4 + skb) * 64 + sn) * 8);
        }
        if (NITER > 2) loadA(2, a2);
        LBAR();
    }

#define REGION(IT, CUR, AR)                                                       \
    {                                                                             \
        const int itc = (IT);                                                     \
        if (itc + 1 < NITER)                                                      \
            *(f16x8*)((_Float16*)(smem + ((CUR) ^ 1) * 5120) + sdst) = sb;        \
        const _Float16* rb = (const _Float16*)(smem + (CUR) * 5120);              \
        f16x8 bf[4];                                                              \
        _Pragma("unroll")                                                         \
        for (int t = 0; t < 4; ++t)                                               \
            bf[t] = *(const f16x8*)(rb + (t * 16 + ln15) * 40 + lhi * 8);         \
        if (itc + 2 < NITER)                                                      \
            sb = *(const f16x8*)(wp +                                             \
                     (size_t)(((itc + 2) * 4 + skb) * 64 + sn) * 8);              \
        _Pragma("unroll")                                                         \
        for (int t = 0; t < 4; ++t)                                               \
            _Pragma("unroll")                                                     \
            for (int q = 0; q < 2; ++q)                                           \
                acc[q][t] = __builtin_amdgcn_mfma_f32_16x16x32_f16(AR[q], bf[t], acc[q][t], 0, 0, 0); \
        if (itc + 3 < NITER) loadA(itc + 3, AR);                                  \
        LBAR();                                                                   \
    }

    for (int it = 0; it < NITER; it += 6) {
        REGION(it, 0, a0);
        if (it + 1 < NITER) REGION(it + 1, 1, a1);
        if (it + 2 < NITER) REGION(it + 2, 0, a2);
        if (it + 3 < NITER) REGION(it + 3, 1, a0);
        if (it + 4 < NITER) REGION(it + 4, 0, a1);
        if (it + 5 < NITER) REGION(it + 5, 1, a2);
    }
#undef REGION

    // ---- per-block per-channel (sum,sumsq) partials (masked rows) ----
#pragma unroll
    for (int t = 0; t < 4; ++t) {
        float s = 0.f, s2 = 0.f;
#pragma unroll
        for (int q = 0; q < 2; ++q)
#pragma unroll
            for (int r = 0; r < 4; ++r) {
                float v = ((vmask >> (q * 4 + r)) & 1u) ? acc[q][t][r] : 0.f;
                s += v; s2 += v * v;
            }
        red[(ln15 + 16 * t) * 17 + (wv * 4 + lhi)] = make_float2(s, s2);
    }
    __syncthreads();
    if (tid < 64) {
        float s = 0.f, s2 = 0.f;
#pragma unroll
        for (int q = 0; q < 16; ++q) { float2 v = red[tid * 17 + q]; s += v.x; s2 += v.y; }
        part[((size_t)blockIdx.z * 64 + tid) * gridDim.x + bx] = make_float2(s, s2);
    }

    // ---- NHWC fp16 output ----
    _Float16* zout = out + (size_t)blockIdx.z * outZstride;
#pragma unroll
    for (int q = 0; q < 2; ++q) {
        const int mbase = bx * 128 + wv * 32 + q * 16 + lhi * 4;
        if (POOL) {
            if (mbase < M) {
                int quad = mbase >> 2;
                const int cpi = H2c * W2c;
                int nb2  = quad / cpi;
                int rem  = quad - nb2 * cpi;
                int h2 = rem / W2c, w2 = rem - h2 * W2c;
                if (h2 < H2 && w2 < W2) {
                    _Float16* op = zout + ((size_t)(nb2 * H2 + h2) * W2 + w2) * Cout;
#pragma unroll
                    for (int t = 0; t < 4; ++t) {
                        int n = ln15 + 16 * t;
                        if (n < Cout) {
                            float mx = fmaxf(fmaxf(acc[q][t][0], acc[q][t][1]),
                                             fmaxf(acc[q][t][2], acc[q][t][3]));
                            op[n] = (_Float16)mx;
                        }
                    }
                }
            }
        } else {
#pragma unroll
            for (int r = 0; r < 4; ++r) {
                int m = mbase + r;
                if (m < M) {
                    _Float16* op = zout + (size_t)m * Cout;
#pragma unroll
                    for (int t = 0; t < 4; ++t) {
                        int n = ln15 + 16 * t;
                        if (n < Cout) op[n] = (_Float16)acc[q][t][r];
                    }
                }
            }
        }
    }
}

// partials -> (mean, rsqrt(var+eps)) per (z,channel)
__global__ __launch_bounds__(256) void bn_finalize(const float2* __restrict__ part,
                                                   int nblkx, double Ninv,
                                                   float2* __restrict__ stats)
{
    __shared__ double sh[512];
    const int zc = blockIdx.x, tid = threadIdx.x;
    const float2* p = part + (size_t)zc * nblkx;
    double s = 0, s2 = 0;
    for (int i = tid; i < nblkx; i += 256) { s += p[i].x; s2 += p[i].y; }
    sh[tid] = s; sh[256 + tid] = s2;
    __syncthreads();
    for (int st = 128; st > 0; st >>= 1) {
        if (tid < st) { sh[tid] += sh[tid + st]; sh[256 + tid] += sh[256 + tid + st]; }
        __syncthreads();
    }
    if (tid == 0) {
        float mean = (float)(sh[0] * Ninv);
        float var  = (float)(sh[256] * Ninv - (double)mean * (double)mean);
        if (var < 0.f) var = 0.f;
        stats[zc] = make_float2(mean, rsqrtf(var + 1e-5f));
    }
}

// raw NHWC fp16 + stats -> padded NHWC fp16 with zero border.
__global__ void bn_split(const _Float16* __restrict__ raw, const float2* __restrict__ stats,
                         _Float16* __restrict__ outF, int H, int W, int total)
{
    int idx = blockIdx.x * 256 + threadIdx.x;
    if (idx >= total) return;
    const int Hp = H + 2, Wp = W + 2;
    int c4 = idx & 15;
    int t  = idx >> 4;
    int wp = t % Wp; t /= Wp;
    int hp = t % Hp; int img = t / Hp;
    size_t o = (((size_t)img * Hp + hp) * Wp + wp) * 64 + c4 * 4;
    f16x4 hi;
    if (hp == 0 || hp == Hp - 1 || wp == 0 || wp == Wp - 1) {
#pragma unroll
        for (int j = 0; j < 4; ++j) hi[j] = (_Float16)0.f;
    } else {
        f16x4 v = *(const f16x4*)(raw + (((size_t)img * H + (hp - 1)) * W + (wp - 1)) * 64 + c4 * 4);
        const float2* st = stats + (img >> 4) * 64 + c4 * 4;
#pragma unroll
        for (int j = 0; j < 4; ++j) {
            float2 s = st[j];
            hi[j] = (_Float16)fmaxf(((float)v[j] - s.x) * s.y, 0.f);
        }
    }
    *(f16x4*)(outF + o) = hi;
}

// pooled fp16 [P][16][H][W][64] + stats + d -> XB padded fp16
__global__ void mix_split(const _Float16* __restrict__ pooled, const float2* __restrict__ stats,
                          const float* __restrict__ d, _Float16* __restrict__ outF,
                          int H, int W, int P, long strideP, int total)
{
    int idx = blockIdx.x * 256 + threadIdx.x;
    if (idx >= total) return;
    const int Hp = H + 2, Wp = W + 2;
    int c4 = idx & 15;
    int t  = idx >> 4;
    int wp = t % Wp; t /= Wp;
    int hp = t % Hp; t /= Hp;
    int n  = t & 15;
    int cc = t >> 4;
    size_t o = (((size_t)(cc * 16 + n) * Hp + hp) * Wp + wp) * 64 + c4 * 4;
    f16x4 hi;
    if (hp == 0 || hp == Hp - 1 || wp == 0 || wp == Wp - 1) {
#pragma unroll
        for (int j = 0; j < 4; ++j) hi[j] = (_Float16)0.f;
    } else {
        float a[4] = {0.f, 0.f, 0.f, 0.f};
        const _Float16* pb = pooled + (((size_t)n * H + (hp - 1)) * W + (wp - 1)) * 64 + c4 * 4;
        for (int p = 0; p < P; ++p) {
            f16x4 v = *(const f16x4*)(pb + (size_t)p * strideP);
            const float2* st = stats + p * 64 + c4 * 4;
            float dc = d[cc * P + p];
#pragma unroll
            for (int j = 0; j < 4; ++j) {
                float2 s = st[j];
                a[j] = fmaf(dc, fmaxf(((float)v[j] - s.x) * s.y, 0.f), a[j]);
            }
        }
#pragma unroll
        for (int j = 0; j < 4; ++j) hi[j] = (_Float16)a[j];
    }
    *(f16x4*)(outF + o) = hi;
}

// L3 mix: pooled fp16 [16][16][7][7][32] -> XB3 fp32 [40][16][7][7][32]
__global__ void mix_last(const _Float16* __restrict__ pooled, const float2* __restrict__ stats,
                         const float* __restrict__ d, float* __restrict__ out, int total)
{
    int idx = blockIdx.x * 256 + threadIdx.x;
    if (idx >= total) return;
    int c  = idx & 31;
    int t  = idx >> 5;
    int hw = t % 49; t /= 49;
    int n  = t & 15;
    int a  = t >> 4;
    float acc = 0.f;
    const _Float16* pb = pooled + ((size_t)n * 49 + hw) * 32 + c;
    for (int p = 0; p < 16; ++p) {
        float2 s = stats[p * 64 + c];
        acc = fmaf(d[a * 16 + p], fmaxf(((float)pb[(size_t)p * 25088] - s.x) * s.y, 0.f), acc);
    }
    out[idx] = acc;
}

// x NCHW [16][3][256][256] -> packed NHWC4 fp16 [16][256][256][4]
__global__ void prep_x(const float* __restrict__ x, _Float16* __restrict__ xF)
{
    int idx = blockIdx.x * 256 + threadIdx.x;   // 16*65536
    if (idx >= 16 * 65536) return;
    int n = idx >> 16, hw = idx & 65535;
    f16x4 hi;
#pragma unroll
    for (int ci = 0; ci < 3; ++ci)
        hi[ci] = (_Float16)x[((size_t)n * 3 + ci) * 65536 + hw];
    hi[3] = (_Float16)0.f;
    *(f16x4*)(xF + (size_t)idx * 4) = hi;
}

// conv1 weights [64][3][7][7] -> fp16 panel [28 kblk][64][8], k=kh*32+kw*4+ci
__global__ void wtrans1(const float* __restrict__ w, _Float16* __restrict__ wt)
{
    int i = blockIdx.x * 256 + threadIdx.x;
    if (i >= 28 * 512) return;
    int j = i & 7, n = (i >> 3) & 63, kb = i >> 9;
    int k = kb * 8 + j;
    int kh = k >> 5, r = k & 31, kw = r >> 2, ci = r & 3;
    float v = (kw < 7 && ci < 3) ? w[((n * 3 + ci) * 7 + kh) * 7 + kw] : 0.f;
    wt[i] = (_Float16)v;
}

// 3x3 weights [P][Cout][64][3][3] -> fp16 panels [p][72 kblk][64][8]
__global__ void wtrans3(const float* __restrict__ w, _Float16* __restrict__ wt,
                        int P, int Cout)
{
    int total = P * 72 * 512;
    for (int i = blockIdx.x * 256 + threadIdx.x; i < total; i += gridDim.x * 256) {
        int j = i & 7, n = (i >> 3) & 63, kb = (i >> 9) % 72, p = (i >> 9) / 72;
        int k = kb * 8 + j;
        int ci = k & 63, tap = k >> 6, kh = tap / 3, kw = tap - 3 * kh;
        float v = (n < Cout) ? w[(((size_t)(p * Cout + n)) * 64 + ci) * 9 + kh * 3 + kw] : 0.f;
        wt[i] = (_Float16)v;
    }
}

// d = softmax_p( log(softmax_p(br*2)) / t ) for all 4 layers
__global__ void dcalc(const float* __restrict__ br0, const float* __restrict__ br1,
                      const float* __restrict__ br2, const float* __restrict__ br3,
                      const void* __restrict__ tptr, float* __restrict__ D)
{
    const int L = blockIdx.x;
    const float* br; int C, P, off;
    if      (L == 0) { br = br0; C = 4;  P = 2;  off = 0;   }
    else if (L == 1) { br = br1; C = 8;  P = 4;  off = 8;   }
    else if (L == 2) { br = br2; C = 16; P = 8;  off = 40;  }
    else             { br = br3; C = 40; P = 16; off = 168; }
    int ti = *(const int*)tptr;
    float t = (ti > 0 && ti < 1000000) ? (float)ti : *(const float*)tptr;
    const int c = threadIdx.x;
    if (c >= C) return;
    float u[16];
    float mx = -1e30f;
#pragma unroll
    for (int p = 0; p < 16; ++p) if (p < P) { u[p] = br[c * P + p] * 2.0f; mx = fmaxf(mx, u[p]); }
    float se = 0.f;
#pragma unroll
    for (int p = 0; p < 16; ++p) if (p < P) se += expf(u[p] - mx);
    float lse = mx + logf(se);
    float mx2 = -1e30f;
#pragma unroll
    for (int p = 0; p < 16; ++p) if (p < P) { u[p] = (u[p] - lse) / t; mx2 = fmaxf(mx2, u[p]); }
    float se2 = 0.f;
#pragma unroll
    for (int p = 0; p < 16; ++p) if (p < P) { u[p] = expf(u[p] - mx2); se2 += u[p]; }
#pragma unroll
    for (int p = 0; p < 16; ++p) if (p < P) D[off + c * P + p] = u[p] / se2;
}

// h1[a,b,i] = relu( sum_f f[a,b,f]*fw1[a,f,i] + fb1[a,i] ); f stored (h,w,c),
// fw1 indexed (c,h,w)
__global__ __launch_bounds__(128) void fc1_k(const float* __restrict__ f,
                                             const float* __restrict__ w1,
                                             const float* __restrict__ b1,
                                             float* __restrict__ h1)
{
    const int a = blockIdx.x >> 4;
    const int b = blockIdx.x & 15;
    const int i = threadIdx.x;
    const float* fv = f + ((size_t)a * 16 + b) * 1568;
    const float* wv = w1 + (size_t)a * 1568 * 128 + i;
    float acc = b1[a * 128 + i];
    for (int hw = 0; hw < 49; ++hw)
        for (int c = 0; c < 32; ++c)
            acc = fmaf(fv[hw * 32 + c], wv[(size_t)(c * 49 + hw) * 128], acc);
    h1[((size_t)a * 16 + b) * 128 + i] = fmaxf(acc, 0.f);
}

__global__ __launch_bounds__(128) void fc23_k(const float* __restrict__ h1,
                                              const float* __restrict__ w2,
                                              const float* __restrict__ b2,
                                              const float* __restrict__ w3,
                                              const float* __restrict__ b3,
                                              float* __restrict__ out)
{
    __shared__ float sh1[16][128];
    __shared__ float sh2[16][128];
    const int a = blockIdx.x;
    const int i = threadIdx.x;
    for (int b = 0; b < 16; ++b) sh1[b][i] = h1[((size_t)a * 16 + b) * 128 + i];
    __syncthreads();
    float acc[16];
#pragma unroll
    for (int b = 0; b < 16; ++b) acc[b] = b2[a * 128 + i];
    for (int ff = 0; ff < 128; ++ff) {
        float wv = w2[((size_t)a * 128 + ff) * 128 + i];
#pragma unroll
        for (int b = 0; b < 16; ++b) acc[b] = fmaf(sh1[b][ff], wv, acc[b]);
    }
    for (int b = 0; b < 16; ++b) sh2[b][i] = fmaxf(acc[b], 0.f);
    __syncthreads();
    if (i < 16) {
        float o = b3[a];
        for (int ff = 0; ff < 128; ++ff) o = fmaf(sh2[i][ff], w3[a * 128 + ff], o);
        out[i * 40 + a] = o;
    }
}

extern "C" void kernel_launch(void* const* d_in, const int* in_sizes, int n_in,
                              void* d_out, int out_size, void* d_ws, size_t ws_size,
                              hipStream_t stream)
{
    (void)in_sizes; (void)n_in;

    const float* x   = (const float*)d_in[0];
    const float* w10 = (const float*)d_in[1];
    const float* wa[4] = {(const float*)d_in[3],  (const float*)d_in[7],
                          (const float*)d_in[11], (const float*)d_in[15]};
    const float* wb[4] = {(const float*)d_in[5],  (const float*)d_in[9],
                          (const float*)d_in[13], (const float*)d_in[17]};
    const float* br[4] = {(const float*)d_in[19], (const float*)d_in[20],
                          (const float*)d_in[21], (const float*)d_in[22]};
    const float* fw1 = (const float*)d_in[23];
    const float* fb1 = (const float*)d_in[24];
    const float* fw2 = (const float*)d_in[25];
    const float* fb2 = (const float*)d_in[26];
    const float* fw3 = (const float*)d_in[27];
    const float* fb3 = (const float*)d_in[28];
    float* out = (float*)d_out;

    const int Pl[4]  = {2, 4, 8, 16};
    const int CBs[4] = {64, 64, 64, 32};

    // ---- workspace arenas (f32 units); total ~47.0M f32 = 188 MB ----
    const size_t NEED = 47000000ull * 4ull;
    if (ws_size < NEED) {
        hipMemsetAsync(d_out, 0, (size_t)out_size * sizeof(float), stream);
        return;
    }
    float* ws = (float*)d_ws;
    size_t o = 0;
    _Float16* WT1 = (_Float16*)(ws + o); o += 7168;
    _Float16 *WTA[4], *WTB[4];
    for (int L = 0; L < 4; ++L) {
        WTA[L] = (_Float16*)(ws + o); o += (size_t)Pl[L] * 18432;
        WTB[L] = (_Float16*)(ws + o); o += (size_t)Pl[L] * 18432;
    }
    float*  D     = ws + o; o += 1024;
    float2* STATS = (float2*)(ws + o); o += 4352;
    float2* STATS_C1 = STATS;
    float2* STATS_A  = STATS + 64;     // up to 128 entries (z-batched L0)
    float2* STATS_B  = STATS + 1088;
    float*  H1 = ws + o; o += 81920;
    float*  A6 = ws + o; o += 524288;      // conv partials
    float*  A5 = ws + o; o += 4000000;     // pooled fp16 / conv1 partials
    float*  A4 = ws + o; o += 16000000;    // raw conv outputs fp16 NHWC
    float*  A3 = ws + o; o += 16600000;    // fp16 split buf / xc
    float*  A2 = ws + o; o += 8400000;     // fp16 Y / XB chain / XB3 fp32

    float2* PART   = (float2*)A6;
    float2* PARTC1 = (float2*)A5;          // conv1: 64x7813 float2 fits 4M f32
    _Float16* xcF = (_Float16*)A3;
    _Float16* A2F = (_Float16*)A2;
    _Float16* A3F = (_Float16*)A3;
    _Float16* A4F = (_Float16*)A4;
    _Float16* A5F = (_Float16*)A5;

    // ---- weights + mix coefficients + conv1 input prep ----
    prep_x<<<4096, 256, 0, stream>>>(x, xcF);
    wtrans1<<<56, 256, 0, stream>>>(w10, WT1);
    for (int L = 0; L < 4; ++L) {
        int tA = Pl[L] * 72 * 512;
        wtrans3<<<DIVUP(tA, 256), 256, 0, stream>>>(wa[L], WTA[L], Pl[L], 64);
        wtrans3<<<DIVUP(tA, 256), 256, 0, stream>>>(wb[L], WTB[L], Pl[L], CBs[L]);
    }
    dcalc<<<4, 64, 0, stream>>>(br[0], br[1], br[2], br[3], d_in[29], D);

    // ---- conv1: xc -> pooled raw fp16 A4 [16,125,125,64] + stats ----
    conv_mfma<1, 1, 256, 256, 250, 250, 64, 1000000, 7, 125, 125, 125, 125>
        <<<dim3(7813, 1, 1), 256, 0, stream>>>(xcF, 0, WT1, A4F, 0, PARTC1);
    bn_finalize<<<64, 256, 0, stream>>>(PARTC1, 7813, 1.0 / 1000000.0, STATS_C1);
    bn_split<<<DIVUP(16 * 127 * 127 * 16, 256), 256, 0, stream>>>(
        A4F, STATS_C1, A2F, 125, 125, 16 * 127 * 127 * 16);

    // ---- layer 0: both parents z-batched (shared input Y) ----
    conv_mfma<0, 0, 127, 127, 125, 125, 64, 250000, 18, 0, 0, 1, 1>
        <<<dim3(1954, 1, 2), 256, 0, stream>>>(
            A2F, 0, WTA[0], A4F, 16000000, PART);
    bn_finalize<<<128, 256, 0, stream>>>(PART, 1954, 1.0 / 250000.0, STATS_A);
    bn_split<<<DIVUP(2 * 16 * 127 * 127 * 16, 256), 256, 0, stream>>>(
        A4F, STATS_A, A3F, 125, 125, 2 * 16 * 127 * 127 * 16);
    conv_mfma<1, 0, 127, 127, 125, 125, 64, 254016, 18, 62, 62, 63, 63>
        <<<dim3(1985, 1, 2), 256, 0, stream>>>(
            A3F, 16516096, WTB[0], A5F, 3936256, PART);
    bn_finalize<<<128, 256, 0, stream>>>(PART, 1985, 1.0 / 250000.0, STATS_B);
    mix_split<<<DIVUP(4 * 16 * 64 * 64 * 16, 256), 256, 0, stream>>>(
        A5F, STATS_B, D + 0, A2F, 62, 62, 2, 3936256, 4 * 16 * 64 * 64 * 16);

    // ---- layer 1 (z=4) ----
    conv_mfma<0, 0, 64, 64, 62, 62, 64, 61504, 18, 0, 0, 1, 1>
        <<<dim3(481, 1, 4), 256, 0, stream>>>(
            A2F, 4194304, WTA[1], A4F, 3936256, PART);
    bn_finalize<<<256, 256, 0, stream>>>(PART, 481, 1.0 / 61504.0, STATS_A);
    bn_split<<<DIVUP(64 * 64 * 64 * 16, 256), 256, 0, stream>>>(
        A4F, STATS_A, A3F, 62, 62, 64 * 64 * 64 * 16);
    conv_mfma<1, 0, 64, 64, 62, 62, 64, 61504, 18, 31, 31, 31, 31>
        <<<dim3(481, 1, 4), 256, 0, stream>>>(
            A3F, 4194304, WTB[1], A5F, 984064, PART);
    bn_finalize<<<256, 256, 0, stream>>>(PART, 481, 1.0 / 61504.0, STATS_B);
    mix_split<<<DIVUP(8 * 16 * 33 * 33 * 16, 256), 256, 0, stream>>>(
        A5F, STATS_B, D + 8, A2F, 31, 31, 4, 984064, 8 * 16 * 33 * 33 * 16);

    // ---- layer 2 (z=8) ----
    conv_mfma<0, 0, 33, 33, 31, 31, 64, 15376, 18, 0, 0, 1, 1>
        <<<dim3(121, 1, 8), 256, 0, stream>>>(
            A2F, 1115136, WTA[2], A4F, 984064, PART);
    bn_finalize<<<512, 256, 0, stream>>>(PART, 121, 1.0 / 15376.0, STATS_A);
    bn_split<<<DIVUP(128 * 33 * 33 * 16, 256), 256, 0, stream>>>(
        A4F, STATS_A, A3F, 31, 31, 128 * 33 * 33 * 16);
    conv_mfma<1, 0, 33, 33, 31, 31, 64, 16384, 18, 15, 15, 16, 16>
        <<<dim3(128, 1, 8), 256, 0, stream>>>(
            A3F, 1115136, WTB[2], A5F, 230400, PART);
    bn_finalize<<<512, 256, 0, stream>>>(PART, 128, 1.0 / 15376.0, STATS_B);
    mix_split<<<DIVUP(16 * 16 * 17 * 17 * 16, 256), 256, 0, stream>>>(
        A5F, STATS_B, D + 40, A2F, 15, 15, 8, 230400, 16 * 16 * 17 * 17 * 16);

    // ---- layer 3 (z=16) ----
    conv_mfma<0, 0, 17, 17, 15, 15, 64, 3600, 18, 0, 0, 1, 1>
        <<<dim3(29, 1, 16), 256, 0, stream>>>(
            A2F, 295936, WTA[3], A4F, 230400, PART);
    bn_finalize<<<1024, 256, 0, stream>>>(PART, 29, 1.0 / 3600.0, STATS_A);
    bn_split<<<DIVUP(256 * 17 * 17 * 16, 256), 256, 0, stream>>>(
        A4F, STATS_A, A3F, 15, 15, 256 * 17 * 17 * 16);
    conv_mfma<1, 0, 17, 17, 15, 15, 32, 4096, 18, 7, 7, 8, 8>
        <<<dim3(32, 1, 16), 256, 0, stream>>>(
            A3F, 295936, WTB[3], A5F, 25088, PART);
    bn_finalize<<<1024, 256, 0, stream>>>(PART, 32, 1.0 / 3600.0, STATS_B);
    mix_last<<<DIVUP(40 * 16 * 49 * 32, 256), 256, 0, stream>>>(
        A5F, STATS_B, D + 168, A2, 40 * 16 * 49 * 32);

    // ---- FC heads ----
    fc1_k<<<640, 128, 0, stream>>>(A2, fw1, fb1, H1);
    fc23_k<<<40, 128, 0, stream>>>(H1, fw2, fb2, fw3, fb3, out);
}

// Round 22
// 642.053 us; speedup vs baseline: 1.1544x; 1.0720x over previous
//
#include <hip/hip_runtime.h>
#include <math.h>

#define DIVUP(a,b) (((a)+(b)-1)/(b))

typedef _Float16 f16x8 __attribute__((ext_vector_type(8)));
typedef _Float16 f16x4 __attribute__((ext_vector_type(4)));
typedef float    f32x4 __attribute__((ext_vector_type(4)));

// K-loop barrier: LDS-only wait + raw barrier (vmcnt stays in flight).
#define LBAR() do { asm volatile("s_waitcnt lgkmcnt(0)" ::: "memory"); \
                    __builtin_amdgcn_s_barrier(); } while (0)

// ---------------------------------------------------------------------------
// Implicit-GEMM conv, NHWC, single-fp16 MFMA: A fp16, W fp16, fp32 accum,
// fp16 OUTPUT. 8 MFMA / wave / K-step. BM=128, BN=64, BK=32. Geometry
// compile-time. R19 configuration = measured best (636 us).
// A: direct global->VGPR frag layout, 3-deep register pipeline, unconditional
//    loads. B: LDS [64][40] double-buffered, lgkm-only barrier per K-step.
// launch_bounds(256,4): 4 blocks/CU is the cache-equilibrium point —
// (256,6) raised occupancy to 56% but doubled HBM traffic (L2 thrash) and
// squeezed the A-pipeline (VGPR 48->40): 636->688 us. (256,8) spilled: 1765.
// XCD bijective swizzle (m204). POOL=1: quad-M + fused 2x2 maxpool.
// ---------------------------------------------------------------------------
template<int POOL, int C1, int HinP, int WinP, int Hout, int Wout, int Cout,
         int M, int NITER, int H2, int W2, int H2c, int W2c>
__global__ __launch_bounds__(256, 4) void conv_mfma(
    const _Float16* __restrict__ in, long inZstride,
    const _Float16* __restrict__ wt,
    _Float16* __restrict__ out, long outZstride, float2* __restrict__ part)
{
    __shared__ __align__(16) char smem[10240];   // B dbuf: 2 x 5120; red overlay
    float2* red = (float2*)smem;                 // [64][17] after K-loop

    // ---- bijective XCD swizzle (m204) ----
    int bx;
    {
        int n = gridDim.x, orig = blockIdx.x;
        int q = n >> 3, r = n & 7;
        int xcd = orig & 7, idx = orig >> 3;
        bx = (xcd < r ? xcd * (q + 1) : r * (q + 1) + (xcd - r) * q) + idx;
    }

    const int tid  = threadIdx.x;
    const int wv   = tid >> 6;
    const int ln15 = tid & 15;
    const int lhi  = (tid >> 4) & 3;
    const int sn   = tid & 63;        // B stage: n row this thread stages
    const int skb  = tid >> 6;        // B stage: kb slot
    const int sdst = sn * 40 + skb * 8;

    const _Float16* ip = in + (size_t)blockIdx.z * inZstride;

    auto pixbase = [&](int mA) -> int {
        int nb, h, w; bool valid;
        if (POOL) {
            int r = mA & 3, quad = mA >> 2;
            const int cpi = H2c * W2c;
            nb = quad / cpi;
            int rem = quad - nb * cpi;
            int h2 = rem / W2c, w2 = rem - h2 * W2c;
            h = h2 * 2 + (r >> 1); w = w2 * 2 + (r & 1);
            valid = (mA < M) && (h < Hout) && (w < Wout);
        } else {
            const int HW = Hout * Wout;
            valid = mA < M;
            int mm = valid ? mA : 0;
            nb = mm / HW;
            int rem = mm - nb * HW;
            h = rem / Wout; w = rem - h * Wout;
        }
        if (!valid) { nb = 0; h = 0; w = 0; }
        if (C1) return ((nb * 256 + h) * 256 + w) * 4;
        return ((nb * HinP + h) * WinP + w) * 64;
    };
    auto rowvalid = [&](int mA) -> bool {
        if (POOL) {
            int r = mA & 3, quad = mA >> 2;
            const int cpi = H2c * W2c;
            int nb = quad / cpi;
            int rem = quad - nb * cpi;
            int h2 = rem / W2c, w2 = rem - h2 * W2c;
            int h = h2 * 2 + (r >> 1), w = w2 * 2 + (r & 1);
            return (mA < M) && (h < Hout) && (w < Wout);
        }
        return mA < M;
    };

    int abase[2];
#pragma unroll
    for (int q = 0; q < 2; ++q)
        abase[q] = pixbase(bx * 128 + wv * 32 + q * 16 + ln15);

    unsigned vmask = 0;
#pragma unroll
    for (int q = 0; q < 2; ++q)
#pragma unroll
        for (int r = 0; r < 4; ++r)
            vmask |= (unsigned)rowvalid(bx * 128 + wv * 32 + q * 16 + lhi * 4 + r)
                     << (q * 4 + r);

    const _Float16* wp = wt + (size_t)blockIdx.z * NITER * 2048;

    auto loadA = [&](int it, f16x8 (&a)[2]) {
        int off;
        if (C1) off = it * 1024 + lhi * 8;
        else { int tap = it >> 1; int kh = tap / 3, kw = tap - 3 * kh;
               off = (kh * WinP + kw) * 64 + (it & 1) * 32 + lhi * 8; }
#pragma unroll
        for (int q = 0; q < 2; ++q)
            a[q] = *(const f16x8*)(ip + abase[q] + off);
    };

    f32x4 acc[2][4] = {};
    f16x8 a0[2], a1[2], a2[2];
    f16x8 sb;

    // ---- prologue: buf0 <- B(0); a0/a1/a2 <- A(0..2); sb <- B(1) ----
    {
        f16x8 h = *(const f16x8*)(wp + (size_t)(skb * 64 + sn) * 8);
        *(f16x8*)((_Float16*)smem + sdst) = h;
        loadA(0, a0);
        if (NITER > 1) {
            loadA(1, a1);
            sb = *(const f16x8*)(wp + (size_t)((4 + skb) * 64 + sn) * 8);
        }
        if (NITER > 2) loadA(2, a2);
        LBAR();
    }

#define REGION(IT, CUR, AR)                                                       \
    {                                                                             \
        const int itc = (IT);                                                     \
        if (itc + 1 < NITER)                                                      \
            *(f16x8*)((_Float16*)(smem + ((CUR) ^ 1) * 5120) + sdst) = sb;        \
        const _Float16* rb = (const _Float16*)(smem + (CUR) * 5120);              \
        f16x8 bf[4];                                                              \
        _Pragma("unroll")                                                         \
        for (int t = 0; t < 4; ++t)                                               \
            bf[t] = *(const f16x8*)(rb + (t * 16 + ln15) * 40 + lhi * 8);         \
        if (itc + 2 < NITER)                                                      \
            sb = *(const f16x8*)(wp +                                             \
                     (size_t)(((itc + 2) * 4 + skb) * 64 + sn) * 8);              \
        _Pragma("unroll")                                                         \
        for (int t = 0; t < 4; ++t)                                               \
            _Pragma("unroll")                                                     \
            for (int q = 0; q < 2; ++q)                                           \
                acc[q][t] = __builtin_amdgcn_mfma_f32_16x16x32_f16(AR[q], bf[t], acc[q][t], 0, 0, 0); \
        if (itc + 3 < NITER) loadA(itc + 3, AR);                                  \
        LBAR();                                                                   \
    }

    for (int it = 0; it < NITER; it += 6) {
        REGION(it, 0, a0);
        if (it + 1 < NITER) REGION(it + 1, 1, a1);
        if (it + 2 < NITER) REGION(it + 2, 0, a2);
        if (it + 3 < NITER) REGION(it + 3, 1, a0);
        if (it + 4 < NITER) REGION(it + 4, 0, a1);
        if (it + 5 < NITER) REGION(it + 5, 1, a2);
    }
#undef REGION

    // ---- per-block per-channel (sum,sumsq) partials (masked rows) ----
#pragma unroll
    for (int t = 0; t < 4; ++t) {
        float s = 0.f, s2 = 0.f;
#pragma unroll
        for (int q = 0; q < 2; ++q)
#pragma unroll
            for (int r = 0; r < 4; ++r) {
                float v = ((vmask >> (q * 4 + r)) & 1u) ? acc[q][t][r] : 0.f;
                s += v; s2 += v * v;
            }
        red[(ln15 + 16 * t) * 17 + (wv * 4 + lhi)] = make_float2(s, s2);
    }
    __syncthreads();
    if (tid < 64) {
        float s = 0.f, s2 = 0.f;
#pragma unroll
        for (int q = 0; q < 16; ++q) { float2 v = red[tid * 17 + q]; s += v.x; s2 += v.y; }
        part[((size_t)blockIdx.z * 64 + tid) * gridDim.x + bx] = make_float2(s, s2);
    }

    // ---- NHWC fp16 output ----
    _Float16* zout = out + (size_t)blockIdx.z * outZstride;
#pragma unroll
    for (int q = 0; q < 2; ++q) {
        const int mbase = bx * 128 + wv * 32 + q * 16 + lhi * 4;
        if (POOL) {
            if (mbase < M) {
                int quad = mbase >> 2;
                const int cpi = H2c * W2c;
                int nb2  = quad / cpi;
                int rem  = quad - nb2 * cpi;
                int h2 = rem / W2c, w2 = rem - h2 * W2c;
                if (h2 < H2 && w2 < W2) {
                    _Float16* op = zout + ((size_t)(nb2 * H2 + h2) * W2 + w2) * Cout;
#pragma unroll
                    for (int t = 0; t < 4; ++t) {
                        int n = ln15 + 16 * t;
                        if (n < Cout) {
                            float mx = fmaxf(fmaxf(acc[q][t][0], acc[q][t][1]),
                                             fmaxf(acc[q][t][2], acc[q][t][3]));
                            op[n] = (_Float16)mx;
                        }
                    }
                }
            }
        } else {
#pragma unroll
            for (int r = 0; r < 4; ++r) {
                int m = mbase + r;
                if (m < M) {
                    _Float16* op = zout + (size_t)m * Cout;
#pragma unroll
                    for (int t = 0; t < 4; ++t) {
                        int n = ln15 + 16 * t;
                        if (n < Cout) op[n] = (_Float16)acc[q][t][r];
                    }
                }
            }
        }
    }
}

// partials -> (mean, rsqrt(var+eps)) per (z,channel)
__global__ __launch_bounds__(256) void bn_finalize(const float2* __restrict__ part,
                                                   int nblkx, double Ninv,
                                                   float2* __restrict__ stats)
{
    __shared__ double sh[512];
    const int zc = blockIdx.x, tid = threadIdx.x;
    const float2* p = part + (size_t)zc * nblkx;
    double s = 0, s2 = 0;
    for (int i = tid; i < nblkx; i += 256) { s += p[i].x; s2 += p[i].y; }
    sh[tid] = s; sh[256 + tid] = s2;
    __syncthreads();
    for (int st = 128; st > 0; st >>= 1) {
        if (tid < st) { sh[tid] += sh[tid + st]; sh[256 + tid] += sh[256 + tid + st]; }
        __syncthreads();
    }
    if (tid == 0) {
        float mean = (float)(sh[0] * Ninv);
        float var  = (float)(sh[256] * Ninv - (double)mean * (double)mean);
        if (var < 0.f) var = 0.f;
        stats[zc] = make_float2(mean, rsqrtf(var + 1e-5f));
    }
}

// raw NHWC fp16 + stats -> padded NHWC fp16 with zero border.
__global__ void bn_split(const _Float16* __restrict__ raw, const float2* __restrict__ stats,
                         _Float16* __restrict__ outF, int H, int W, int total)
{
    int idx = blockIdx.x * 256 + threadIdx.x;
    if (idx >= total) return;
    const int Hp = H + 2, Wp = W + 2;
    int c4 = idx & 15;
    int t  = idx >> 4;
    int wp = t % Wp; t /= Wp;
    int hp = t % Hp; int img = t / Hp;
    size_t o = (((size_t)img * Hp + hp) * Wp + wp) * 64 + c4 * 4;
    f16x4 hi;
    if (hp == 0 || hp == Hp - 1 || wp == 0 || wp == Wp - 1) {
#pragma unroll
        for (int j = 0; j < 4; ++j) hi[j] = (_Float16)0.f;
    } else {
        f16x4 v = *(const f16x4*)(raw + (((size_t)img * H + (hp - 1)) * W + (wp - 1)) * 64 + c4 * 4);
        const float2* st = stats + (img >> 4) * 64 + c4 * 4;
#pragma unroll
        for (int j = 0; j < 4; ++j) {
            float2 s = st[j];
            hi[j] = (_Float16)fmaxf(((float)v[j] - s.x) * s.y, 0.f);
        }
    }
    *(f16x4*)(outF + o) = hi;
}

// pooled fp16 [P][16][H][W][64] + stats + d -> XB padded fp16
__global__ void mix_split(const _Float16* __restrict__ pooled, const float2* __restrict__ stats,
                          const float* __restrict__ d, _Float16* __restrict__ outF,
                          int H, int W, int P, long strideP, int total)
{
    int idx = blockIdx.x * 256 + threadIdx.x;
    if (idx >= total) return;
    const int Hp = H + 2, Wp = W + 2;
    int c4 = idx & 15;
    int t  = idx >> 4;
    int wp = t % Wp; t /= Wp;
    int hp = t % Hp; t /= Hp;
    int n  = t & 15;
    int cc = t >> 4;
    size_t o = (((size_t)(cc * 16 + n) * Hp + hp) * Wp + wp) * 64 + c4 * 4;
    f16x4 hi;
    if (hp == 0 || hp == Hp - 1 || wp == 0 || wp == Wp - 1) {
#pragma unroll
        for (int j = 0; j < 4; ++j) hi[j] = (_Float16)0.f;
    } else {
        float a[4] = {0.f, 0.f, 0.f, 0.f};
        const _Float16* pb = pooled + (((size_t)n * H + (hp - 1)) * W + (wp - 1)) * 64 + c4 * 4;
        for (int p = 0; p < P; ++p) {
            f16x4 v = *(const f16x4*)(pb + (size_t)p * strideP);
            const float2* st = stats + p * 64 + c4 * 4;
            float dc = d[cc * P + p];
#pragma unroll
            for (int j = 0; j < 4; ++j) {
                float2 s = st[j];
                a[j] = fmaf(dc, fmaxf(((float)v[j] - s.x) * s.y, 0.f), a[j]);
            }
        }
#pragma unroll
        for (int j = 0; j < 4; ++j) hi[j] = (_Float16)a[j];
    }
    *(f16x4*)(outF + o) = hi;
}

// L3 mix: pooled fp16 [16][16][7][7][32] -> XB3 fp32 [40][16][7][7][32]
__global__ void mix_last(const _Float16* __restrict__ pooled, const float2* __restrict__ stats,
                         const float* __restrict__ d, float* __restrict__ out, int total)
{
    int idx = blockIdx.x * 256 + threadIdx.x;
    if (idx >= total) return;
    int c  = idx & 31;
    int t  = idx >> 5;
    int hw = t % 49; t /= 49;
    int n  = t & 15;
    int a  = t >> 4;
    float acc = 0.f;
    const _Float16* pb = pooled + ((size_t)n * 49 + hw) * 32 + c;
    for (int p = 0; p < 16; ++p) {
        float2 s = stats[p * 64 + c];
        acc = fmaf(d[a * 16 + p], fmaxf(((float)pb[(size_t)p * 25088] - s.x) * s.y, 0.f), acc);
    }
    out[idx] = acc;
}

// x NCHW [16][3][256][256] -> packed NHWC4 fp16 [16][256][256][4]
__global__ void prep_x(const float* __restrict__ x, _Float16* __restrict__ xF)
{
    int idx = blockIdx.x * 256 + threadIdx.x;   // 16*65536
    if (idx >= 16 * 65536) return;
    int n = idx >> 16, hw = idx & 65535;
    f16x4 hi;
#pragma unroll
    for (int ci = 0; ci < 3; ++ci)
        hi[ci] = (_Float16)x[((size_t)n * 3 + ci) * 65536 + hw];
    hi[3] = (_Float16)0.f;
    *(f16x4*)(xF + (size_t)idx * 4) = hi;
}

// conv1 weights [64][3][7][7] -> fp16 panel [28 kblk][64][8], k=kh*32+kw*4+ci
__global__ void wtrans1(const float* __restrict__ w, _Float16* __restrict__ wt)
{
    int i = blockIdx.x * 256 + threadIdx.x;
    if (i >= 28 * 512) return;
    int j = i & 7, n = (i >> 3) & 63, kb = i >> 9;
    int k = kb * 8 + j;
    int kh = k >> 5, r = k & 31, kw = r >> 2, ci = r & 3;
    float v = (kw < 7 && ci < 3) ? w[((n * 3 + ci) * 7 + kh) * 7 + kw] : 0.f;
    wt[i] = (_Float16)v;
}

// 3x3 weights [P][Cout][64][3][3] -> fp16 panels [p][72 kblk][64][8]
__global__ void wtrans3(const float* __restrict__ w, _Float16* __restrict__ wt,
                        int P, int Cout)
{
    int total = P * 72 * 512;
    for (int i = blockIdx.x * 256 + threadIdx.x; i < total; i += gridDim.x * 256) {
        int j = i & 7, n = (i >> 3) & 63, kb = (i >> 9) % 72, p = (i >> 9) / 72;
        int k = kb * 8 + j;
        int ci = k & 63, tap = k >> 6, kh = tap / 3, kw = tap - 3 * kh;
        float v = (n < Cout) ? w[(((size_t)(p * Cout + n)) * 64 + ci) * 9 + kh * 3 + kw] : 0.f;
        wt[i] = (_Float16)v;
    }
}

// d = softmax_p( log(softmax_p(br*2)) / t ) for all 4 layers
__global__ void dcalc(const float* __restrict__ br0, const float* __restrict__ br1,
                      const float* __restrict__ br2, const float* __restrict__ br3,
                      const void* __restrict__ tptr, float* __restrict__ D)
{
    const int L = blockIdx.x;
    const float* br; int C, P, off;
    if      (L == 0) { br = br0; C = 4;  P = 2;  off = 0;   }
    else if (L == 1) { br = br1; C = 8;  P = 4;  off = 8;   }
    else if (L == 2) { br = br2; C = 16; P = 8;  off = 40;  }
    else             { br = br3; C = 40; P = 16; off = 168; }
    int ti = *(const int*)tptr;
    float t = (ti > 0 && ti < 1000000) ? (float)ti : *(const float*)tptr;
    const int c = threadIdx.x;
    if (c >= C) return;
    float u[16];
    float mx = -1e30f;
#pragma unroll
    for (int p = 0; p < 16; ++p) if (p < P) { u[p] = br[c * P + p] * 2.0f; mx = fmaxf(mx, u[p]); }
    float se = 0.f;
#pragma unroll
    for (int p = 0; p < 16; ++p) if (p < P) se += expf(u[p] - mx);
    float lse = mx + logf(se);
    float mx2 = -1e30f;
#pragma unroll
    for (int p = 0; p < 16; ++p) if (p < P) { u[p] = (u[p] - lse) / t; mx2 = fmaxf(mx2, u[p]); }
    float se2 = 0.f;
#pragma unroll
    for (int p = 0; p < 16; ++p) if (p < P) { u[p] = expf(u[p] - mx2); se2 += u[p]; }
#pragma unroll
    for (int p = 0; p < 16; ++p) if (p < P) D[off + c * P + p] = u[p] / se2;
}

// h1[a,b,i] = relu( sum_f f[a,b,f]*fw1[a,f,i] + fb1[a,i] ); f stored (h,w,c),
// fw1 indexed (c,h,w)
__global__ __launch_bounds__(128) void fc1_k(const float* __restrict__ f,
                                             const float* __restrict__ w1,
                                             const float* __restrict__ b1,
                                             float* __restrict__ h1)
{
    const int a = blockIdx.x >> 4;
    const int b = blockIdx.x & 15;
    const int i = threadIdx.x;
    const float* fv = f + ((size_t)a * 16 + b) * 1568;
    const float* wv = w1 + (size_t)a * 1568 * 128 + i;
    float acc = b1[a * 128 + i];
    for (int hw = 0; hw < 49; ++hw)
        for (int c = 0; c < 32; ++c)
            acc = fmaf(fv[hw * 32 + c], wv[(size_t)(c * 49 + hw) * 128], acc);
    h1[((size_t)a * 16 + b) * 128 + i] = fmaxf(acc, 0.f);
}

__global__ __launch_bounds__(128) void fc23_k(const float* __restrict__ h1,
                                              const float* __restrict__ w2,
                                              const float* __restrict__ b2,
                                              const float* __restrict__ w3,
                                              const float* __restrict__ b3,
                                              float* __restrict__ out)
{
    __shared__ float sh1[16][128];
    __shared__ float sh2[16][128];
    const int a = blockIdx.x;
    const int i = threadIdx.x;
    for (int b = 0; b < 16; ++b) sh1[b][i] = h1[((size_t)a * 16 + b) * 128 + i];
    __syncthreads();
    float acc[16];
#pragma unroll
    for (int b = 0; b < 16; ++b) acc[b] = b2[a * 128 + i];
    for (int ff = 0; ff < 128; ++ff) {
        float wv = w2[((size_t)a * 128 + ff) * 128 + i];
#pragma unroll
        for (int b = 0; b < 16; ++b) acc[b] = fmaf(sh1[b][ff], wv, acc[b]);
    }
    for (int b = 0; b < 16; ++b) sh2[b][i] = fmaxf(acc[b], 0.f);
    __syncthreads();
    if (i < 16) {
        float o = b3[a];
        for (int ff = 0; ff < 128; ++ff) o = fmaf(sh2[i][ff], w3[a * 128 + ff], o);
        out[i * 40 + a] = o;
    }
}

extern "C" void kernel_launch(void* const* d_in, const int* in_sizes, int n_in,
                              void* d_out, int out_size, void* d_ws, size_t ws_size,
                              hipStream_t stream)
{
    (void)in_sizes; (void)n_in;

    const float* x   = (const float*)d_in[0];
    const float* w10 = (const float*)d_in[1];
    const float* wa[4] = {(const float*)d_in[3],  (const float*)d_in[7],
                          (const float*)d_in[11], (const float*)d_in[15]};
    const float* wb[4] = {(const float*)d_in[5],  (const float*)d_in[9],
                          (const float*)d_in[13], (const float*)d_in[17]};
    const float* br[4] = {(const float*)d_in[19], (const float*)d_in[20],
                          (const float*)d_in[21], (const float*)d_in[22]};
    const float* fw1 = (const float*)d_in[23];
    const float* fb1 = (const float*)d_in[24];
    const float* fw2 = (const float*)d_in[25];
    const float* fb2 = (const float*)d_in[26];
    const float* fw3 = (const float*)d_in[27];
    const float* fb3 = (const float*)d_in[28];
    float* out = (float*)d_out;

    const int Pl[4]  = {2, 4, 8, 16};
    const int CBs[4] = {64, 64, 64, 32};

    // ---- workspace arenas (f32 units); total ~47.0M f32 = 188 MB ----
    const size_t NEED = 47000000ull * 4ull;
    if (ws_size < NEED) {
        hipMemsetAsync(d_out, 0, (size_t)out_size * sizeof(float), stream);
        return;
    }
    float* ws = (float*)d_ws;
    size_t o = 0;
    _Float16* WT1 = (_Float16*)(ws + o); o += 7168;
    _Float16 *WTA[4], *WTB[4];
    for (int L = 0; L < 4; ++L) {
        WTA[L] = (_Float16*)(ws + o); o += (size_t)Pl[L] * 18432;
        WTB[L] = (_Float16*)(ws + o); o += (size_t)Pl[L] * 18432;
    }
    float*  D     = ws + o; o += 1024;
    float2* STATS = (float2*)(ws + o); o += 4352;
    float2* STATS_C1 = STATS;
    float2* STATS_A  = STATS + 64;     // up to 128 entries (z-batched L0)
    float2* STATS_B  = STATS + 1088;
    float*  H1 = ws + o; o += 81920;
    float*  A6 = ws + o; o += 524288;      // conv partials
    float*  A5 = ws + o; o += 4000000;     // pooled fp16 / conv1 partials
    float*  A4 = ws + o; o += 16000000;    // raw conv outputs fp16 NHWC
    float*  A3 = ws + o; o += 16600000;    // fp16 split buf / xc
    float*  A2 = ws + o; o += 8400000;     // fp16 Y / XB chain / XB3 fp32

    float2* PART   = (float2*)A6;
    float2* PARTC1 = (float2*)A5;          // conv1: 64x7813 float2 fits 4M f32
    _Float16* xcF = (_Float16*)A3;
    _Float16* A2F = (_Float16*)A2;
    _Float16* A3F = (_Float16*)A3;
    _Float16* A4F = (_Float16*)A4;
    _Float16* A5F = (_Float16*)A5;

    // ---- weights + mix coefficients + conv1 input prep ----
    prep_x<<<4096, 256, 0, stream>>>(x, xcF);
    wtrans1<<<56, 256, 0, stream>>>(w10, WT1);
    for (int L = 0; L < 4; ++L) {
        int tA = Pl[L] * 72 * 512;
        wtrans3<<<DIVUP(tA, 256), 256, 0, stream>>>(wa[L], WTA[L], Pl[L], 64);
        wtrans3<<<DIVUP(tA, 256), 256, 0, stream>>>(wb[L], WTB[L], Pl[L], CBs[L]);
    }
    dcalc<<<4, 64, 0, stream>>>(br[0], br[1], br[2], br[3], d_in[29], D);

    // ---- conv1: xc -> pooled raw fp16 A4 [16,125,125,64] + stats ----
    conv_mfma<1, 1, 256, 256, 250, 250, 64, 1000000, 7, 125, 125, 125, 125>
        <<<dim3(7813, 1, 1), 256, 0, stream>>>(xcF, 0, WT1, A4F, 0, PARTC1);
    bn_finalize<<<64, 256, 0, stream>>>(PARTC1, 7813, 1.0 / 1000000.0, STATS_C1);
    bn_split<<<DIVUP(16 * 127 * 127 * 16, 256), 256, 0, stream>>>(
        A4F, STATS_C1, A2F, 125, 125, 16 * 127 * 127 * 16);

    // ---- layer 0: both parents z-batched (shared input Y) ----
    conv_mfma<0, 0, 127, 127, 125, 125, 64, 250000, 18, 0, 0, 1, 1>
        <<<dim3(1954, 1, 2), 256, 0, stream>>>(
            A2F, 0, WTA[0], A4F, 16000000, PART);
    bn_finalize<<<128, 256, 0, stream>>>(PART, 1954, 1.0 / 250000.0, STATS_A);
    bn_split<<<DIVUP(2 * 16 * 127 * 127 * 16, 256), 256, 0, stream>>>(
        A4F, STATS_A, A3F, 125, 125, 2 * 16 * 127 * 127 * 16);
    conv_mfma<1, 0, 127, 127, 125, 125, 64, 254016, 18, 62, 62, 63, 63>
        <<<dim3(1985, 1, 2), 256, 0, stream>>>(
            A3F, 16516096, WTB[0], A5F, 3936256, PART);
    bn_finalize<<<128, 256, 0, stream>>>(PART, 1985, 1.0 / 250000.0, STATS_B);
    mix_split<<<DIVUP(4 * 16 * 64 * 64 * 16, 256), 256, 0, stream>>>(
        A5F, STATS_B, D + 0, A2F, 62, 62, 2, 3936256, 4 * 16 * 64 * 64 * 16);

    // ---- layer 1 (z=4) ----
    conv_mfma<0, 0, 64, 64, 62, 62, 64, 61504, 18, 0, 0, 1, 1>
        <<<dim3(481, 1, 4), 256, 0, stream>>>(
            A2F, 4194304, WTA[1], A4F, 3936256, PART);
    bn_finalize<<<256, 256, 0, stream>>>(PART, 481, 1.0 / 61504.0, STATS_A);
    bn_split<<<DIVUP(64 * 64 * 64 * 16, 256), 256, 0, stream>>>(
        A4F, STATS_A, A3F, 62, 62, 64 * 64 * 64 * 16);
    conv_mfma<1, 0, 64, 64, 62, 62, 64, 61504, 18, 31, 31, 31, 31>
        <<<dim3(481, 1, 4), 256, 0, stream>>>(
            A3F, 4194304, WTB[1], A5F, 984064, PART);
    bn_finalize<<<256, 256, 0, stream>>>(PART, 481, 1.0 / 61504.0, STATS_B);
    mix_split<<<DIVUP(8 * 16 * 33 * 33 * 16, 256), 256, 0, stream>>>(
        A5F, STATS_B, D + 8, A2F, 31, 31, 4, 984064, 8 * 16 * 33 * 33 * 16);

    // ---- layer 2 (z=8) ----
    conv_mfma<0, 0, 33, 33, 31, 31, 64, 15376, 18, 0, 0, 1, 1>
        <<<dim3(121, 1, 8), 256, 0, stream>>>(
            A2F, 1115136, WTA[2], A4F, 984064, PART);
    bn_finalize<<<512, 256, 0, stream>>>(PART, 121, 1.0 / 15376.0, STATS_A);
    bn_split<<<DIVUP(128 * 33 * 33 * 16, 256), 256, 0, stream>>>(
        A4F, STATS_A, A3F, 31, 31, 128 * 33 * 33 * 16);
    conv_mfma<1, 0, 33, 33, 31, 31, 64, 16384, 18, 15, 15, 16, 16>
        <<<dim3(128, 1, 8), 256, 0, stream>>>(
            A3F, 1115136, WTB[2], A5F, 230400, PART);
    bn_finalize<<<512, 256, 0, stream>>>(PART, 128, 1.0 / 15376.0, STATS_B);
    mix_split<<<DIVUP(16 * 16 * 17 * 17 * 16, 256), 256, 0, stream>>>(
        A5F, STATS_B, D + 40, A2F, 15, 15, 8, 230400, 16 * 16 * 17 * 17 * 16);

    // ---- layer 3 (z=16) ----
    conv_mfma<0, 0, 17, 17, 15, 15, 64, 3600, 18, 0, 0, 1, 1>
        <<<dim3(29, 1, 16), 256, 0, stream>>>(
            A2F, 295936, WTA[3], A4F, 230400, PART);
    bn_finalize<<<1024, 256, 0, stream>>>(PART, 29, 1.0 / 3600.0, STATS_A);
    bn_split<<<DIVUP(256 * 17 * 17 * 16, 256), 256, 0, stream>>>(
        A4F, STATS_A, A3F, 15, 15, 256 * 17 * 17 * 16);
    conv_mfma<1, 0, 17, 17, 15, 15, 32, 4096, 18, 7, 7, 8, 8>
        <<<dim3(32, 1, 16), 256, 0, stream>>>(
            A3F, 295936, WTB[3], A5F, 25088, PART);
    bn_finalize<<<1024, 256, 0, stream>>>(PART, 32, 1.0 / 3600.0, STATS_B);
    mix_last<<<DIVUP(40 * 16 * 49 * 32, 256), 256, 0, stream>>>(
        A5F, STATS_B, D + 168, A2, 40 * 16 * 49 * 32);

    // ---- FC heads ----
    fc1_k<<<640, 128, 0, stream>>>(A2, fw1, fb1, H1);
    fc23_k<<<40, 128, 0, stream>>>(H1, fw2, fb2, fw3, fb3, out);
}

// Round 23
// 632.599 us; speedup vs baseline: 1.1716x; 1.0149x over previous
//
#include <hip/hip_runtime.h>
#include <math.h>

#define DIVUP(a,b) (((a)+(b)-1)/(b))

typedef _Float16 f16x8 __attribute__((ext_vector_type(8)));
typedef _Float16 f16x4 __attribute__((ext_vector_type(4)));
typedef float    f32x4 __attribute__((ext_vector_type(4)));

// K-loop barrier: LDS-only wait + raw barrier (vmcnt stays in flight).
#define LBAR() do { asm volatile("s_waitcnt lgkmcnt(0)" ::: "memory"); \
                    __builtin_amdgcn_s_barrier(); } while (0)

// ---------------------------------------------------------------------------
// Implicit-GEMM conv, NHWC, single-fp16 MFMA: A fp16, W fp16, fp32 accum,
// fp16 OUTPUT. 8 MFMA / wave / K-step. BM=128, BN=64, BK=32. Geometry
// compile-time. R19 base (636 us) + 2D TILING for POOL=0:
//   block = 4-row x 32-col pixel tile (wave wv owns row th*4+wv, cols 0..31).
//   A-halo footprint 65KB -> 26KB/block => 4 blk/CU x 32 CU ~ 3.3MB/XCD
//   < 4MB L2: tap re-reads become L2 hits (the measured cache equilibrium).
// POOL=1 keeps linear quad-ordering (pool-quad fragment constraint).
// A: direct global->VGPR frag layout, 3-deep register pipeline, unconditional
//    loads (invalid clamp to base 0; masked at stats emit + C guards).
// B: LDS [64][40] double-buffered, lgkm-only barrier per K-step.
// launch_bounds(256,4) = cache-equilibrium point ((256,6) thrashed, (256,8)
// spilled). XCD bijective swizzle (m204). POOL=1: quad-M + fused maxpool.
// ---------------------------------------------------------------------------
template<int POOL, int C1, int HinP, int WinP, int Hout, int Wout, int Cout,
         int M, int NITER, int H2, int W2, int H2c, int W2c>
__global__ __launch_bounds__(256, 4) void conv_mfma(
    const _Float16* __restrict__ in, long inZstride,
    const _Float16* __restrict__ wt,
    _Float16* __restrict__ out, long outZstride, float2* __restrict__ part)
{
    __shared__ __align__(16) char smem[10240];   // B dbuf: 2 x 5120; red overlay
    float2* red = (float2*)smem;                 // [64][17] after K-loop

    // ---- bijective XCD swizzle (m204) ----
    int bx;
    {
        int n = gridDim.x, orig = blockIdx.x;
        int q = n >> 3, r = n & 7;
        int xcd = orig & 7, idx = orig >> 3;
        bx = (xcd < r ? xcd * (q + 1) : r * (q + 1) + (xcd - r) * q) + idx;
    }

    const int tid  = threadIdx.x;
    const int wv   = tid >> 6;
    const int ln15 = tid & 15;
    const int lhi  = (tid >> 4) & 3;
    const int sn   = tid & 63;        // B stage: n row this thread stages
    const int skb  = tid >> 6;        // B stage: kb slot
    const int sdst = sn * 40 + skb * 8;

    const _Float16* ip = in + (size_t)blockIdx.z * inZstride;

    // ---- geometry ----
    // POOL=0: 2D tile decomposition. POOL=1: linear quad ordering (as R19).
    constexpr int HtX = (Hout + 3) / 4;    // row tiles (POOL=0)
    constexpr int WtX = (Wout + 31) / 32;  // col tiles (POOL=0)

    int nbT = 0, thT = 0, twT = 0;         // tiled decode (POOL=0)
    if (POOL == 0) {
        nbT = bx / (HtX * WtX);
        int rem = bx - nbT * (HtX * WtX);
        thT = rem / WtX;
        twT = rem - thT * WtX;
    }
    const int hrow = thT * 4 + wv;         // this wave's pixel row (POOL=0)

    auto pixbase_pool = [&](int mA) -> int {   // POOL=1 path (quad-ordered)
        int r = mA & 3, quad = mA >> 2;
        const int cpi = H2c * W2c;
        int nb = quad / cpi;
        int rem = quad - nb * cpi;
        int h2 = rem / W2c, w2 = rem - h2 * W2c;
        int h = h2 * 2 + (r >> 1), w = w2 * 2 + (r & 1);
        bool valid = (mA < M) && (h < Hout) && (w < Wout);
        if (!valid) { nb = 0; h = 0; w = 0; }
        if (C1) return ((nb * 256 + h) * 256 + w) * 4;
        return ((nb * HinP + h) * WinP + w) * 64;
    };
    auto rowvalid_pool = [&](int mA) -> bool {
        int r = mA & 3, quad = mA >> 2;
        const int cpi = H2c * W2c;
        int nb = quad / cpi;
        int rem = quad - nb * cpi;
        int h2 = rem / W2c, w2 = rem - h2 * W2c;
        int h = h2 * 2 + (r >> 1), w = w2 * 2 + (r & 1);
        return (mA < M) && (h < Hout) && (w < Wout);
    };

    int abase[2];
    unsigned vmask = 0;
    if (POOL == 0) {
#pragma unroll
        for (int q = 0; q < 2; ++q) {
            int w = twT * 32 + q * 16 + ln15;
            bool v = (hrow < Hout) && (w < Wout);
            abase[q] = v ? ((nbT * HinP + hrow) * WinP + w) * 64 : 0;
        }
#pragma unroll
        for (int q = 0; q < 2; ++q)
#pragma unroll
            for (int r = 0; r < 4; ++r) {
                int w = twT * 32 + q * 16 + lhi * 4 + r;
                vmask |= (unsigned)((hrow < Hout) && (w < Wout)) << (q * 4 + r);
            }
    } else {
#pragma unroll
        for (int q = 0; q < 2; ++q)
            abase[q] = pixbase_pool(bx * 128 + wv * 32 + q * 16 + ln15);
#pragma unroll
        for (int q = 0; q < 2; ++q)
#pragma unroll
            for (int r = 0; r < 4; ++r)
                vmask |= (unsigned)rowvalid_pool(bx * 128 + wv * 32 + q * 16 + lhi * 4 + r)
                         << (q * 4 + r);
    }

    const _Float16* wp = wt + (size_t)blockIdx.z * NITER * 2048;

    auto loadA = [&](int it, f16x8 (&a)[2]) {
        int off;
        if (C1) off = it * 1024 + lhi * 8;
        else { int tap = it >> 1; int kh = tap / 3, kw = tap - 3 * kh;
               off = (kh * WinP + kw) * 64 + (it & 1) * 32 + lhi * 8; }
#pragma unroll
        for (int q = 0; q < 2; ++q)
            a[q] = *(const f16x8*)(ip + abase[q] + off);
    };

    f32x4 acc[2][4] = {};
    f16x8 a0[2], a1[2], a2[2];
    f16x8 sb;

    // ---- prologue: buf0 <- B(0); a0/a1/a2 <- A(0..2); sb <- B(1) ----
    {
        f16x8 h = *(const f16x8*)(wp + (size_t)(skb * 64 + sn) * 8);
        *(f16x8*)((_Float16*)smem + sdst) = h;
        loadA(0, a0);
        if (NITER > 1) {
            loadA(1, a1);
            sb = *(const f16x8*)(wp + (size_t)((4 + skb) * 64 + sn) * 8);
        }
        if (NITER > 2) loadA(2, a2);
        LBAR();
    }

#define REGION(IT, CUR, AR)                                                       \
    {                                                                             \
        const int itc = (IT);                                                     \
        if (itc + 1 < NITER)                                                      \
            *(f16x8*)((_Float16*)(smem + ((CUR) ^ 1) * 5120) + sdst) = sb;        \
        const _Float16* rb = (const _Float16*)(smem + (CUR) * 5120);              \
        f16x8 bf[4];                                                              \
        _Pragma("unroll")                                                         \
        for (int t = 0; t < 4; ++t)                                               \
            bf[t] = *(const f16x8*)(rb + (t * 16 + ln15) * 40 + lhi * 8);         \
        if (itc + 2 < NITER)                                                      \
            sb = *(const f16x8*)(wp +                                             \
                     (size_t)(((itc + 2) * 4 + skb) * 64 + sn) * 8);              \
        _Pragma("unroll")                                                         \
        for (int t = 0; t < 4; ++t)                                               \
            _Pragma("unroll")                                                     \
            for (int q = 0; q < 2; ++q)                                           \
                acc[q][t] = __builtin_amdgcn_mfma_f32_16x16x32_f16(AR[q], bf[t], acc[q][t], 0, 0, 0); \
        if (itc + 3 < NITER) loadA(itc + 3, AR);                                  \
        LBAR();                                                                   \
    }

    for (int it = 0; it < NITER; it += 6) {
        REGION(it, 0, a0);
        if (it + 1 < NITER) REGION(it + 1, 1, a1);
        if (it + 2 < NITER) REGION(it + 2, 0, a2);
        if (it + 3 < NITER) REGION(it + 3, 1, a0);
        if (it + 4 < NITER) REGION(it + 4, 0, a1);
        if (it + 5 < NITER) REGION(it + 5, 1, a2);
    }
#undef REGION

    // ---- per-block per-channel (sum,sumsq) partials (masked rows) ----
#pragma unroll
    for (int t = 0; t < 4; ++t) {
        float s = 0.f, s2 = 0.f;
#pragma unroll
        for (int q = 0; q < 2; ++q)
#pragma unroll
            for (int r = 0; r < 4; ++r) {
                float v = ((vmask >> (q * 4 + r)) & 1u) ? acc[q][t][r] : 0.f;
                s += v; s2 += v * v;
            }
        red[(ln15 + 16 * t) * 17 + (wv * 4 + lhi)] = make_float2(s, s2);
    }
    __syncthreads();
    if (tid < 64) {
        float s = 0.f, s2 = 0.f;
#pragma unroll
        for (int q = 0; q < 16; ++q) { float2 v = red[tid * 17 + q]; s += v.x; s2 += v.y; }
        part[((size_t)blockIdx.z * 64 + tid) * gridDim.x + bx] = make_float2(s, s2);
    }

    // ---- NHWC fp16 output ----
    _Float16* zout = out + (size_t)blockIdx.z * outZstride;
    if (POOL == 0) {
        if (hrow < Hout) {
#pragma unroll
            for (int q = 0; q < 2; ++q) {
                const int wcol0 = twT * 32 + q * 16 + lhi * 4;
#pragma unroll
                for (int r = 0; r < 4; ++r) {
                    int w = wcol0 + r;
                    if (w < Wout) {
                        _Float16* op = zout + ((size_t)(nbT * Hout + hrow) * Wout + w) * Cout;
#pragma unroll
                        for (int t = 0; t < 4; ++t) {
                            int n = ln15 + 16 * t;
                            if (n < Cout) op[n] = (_Float16)acc[q][t][r];
                        }
                    }
                }
            }
        }
    } else {
#pragma unroll
        for (int q = 0; q < 2; ++q) {
            const int mbase = bx * 128 + wv * 32 + q * 16 + lhi * 4;
            if (mbase < M) {
                int quad = mbase >> 2;
                const int cpi = H2c * W2c;
                int nb2  = quad / cpi;
                int rem  = quad - nb2 * cpi;
                int h2 = rem / W2c, w2 = rem - h2 * W2c;
                if (h2 < H2 && w2 < W2) {
                    _Float16* op = zout + ((size_t)(nb2 * H2 + h2) * W2 + w2) * Cout;
#pragma unroll
                    for (int t = 0; t < 4; ++t) {
                        int n = ln15 + 16 * t;
                        if (n < Cout) {
                            float mx = fmaxf(fmaxf(acc[q][t][0], acc[q][t][1]),
                                             fmaxf(acc[q][t][2], acc[q][t][3]));
                            op[n] = (_Float16)mx;
                        }
                    }
                }
            }
        }
    }
}

// partials -> (mean, rsqrt(var+eps)) per (z,channel)
__global__ __launch_bounds__(256) void bn_finalize(const float2* __restrict__ part,
                                                   int nblkx, double Ninv,
                                                   float2* __restrict__ stats)
{
    __shared__ double sh[512];
    const int zc = blockIdx.x, tid = threadIdx.x;
    const float2* p = part + (size_t)zc * nblkx;
    double s = 0, s2 = 0;
    for (int i = tid; i < nblkx; i += 256) { s += p[i].x; s2 += p[i].y; }
    sh[tid] = s; sh[256 + tid] = s2;
    __syncthreads();
    for (int st = 128; st > 0; st >>= 1) {
        if (tid < st) { sh[tid] += sh[tid + st]; sh[256 + tid] += sh[256 + tid + st]; }
        __syncthreads();
    }
    if (tid == 0) {
        float mean = (float)(sh[0] * Ninv);
        float var  = (float)(sh[256] * Ninv - (double)mean * (double)mean);
        if (var < 0.f) var = 0.f;
        stats[zc] = make_float2(mean, rsqrtf(var + 1e-5f));
    }
}

// raw NHWC fp16 + stats -> padded NHWC fp16 with zero border.
__global__ void bn_split(const _Float16* __restrict__ raw, const float2* __restrict__ stats,
                         _Float16* __restrict__ outF, int H, int W, int total)
{
    int idx = blockIdx.x * 256 + threadIdx.x;
    if (idx >= total) return;
    const int Hp = H + 2, Wp = W + 2;
    int c4 = idx & 15;
    int t  = idx >> 4;
    int wp = t % Wp; t /= Wp;
    int hp = t % Hp; int img = t / Hp;
    size_t o = (((size_t)img * Hp + hp) * Wp + wp) * 64 + c4 * 4;
    f16x4 hi;
    if (hp == 0 || hp == Hp - 1 || wp == 0 || wp == Wp - 1) {
#pragma unroll
        for (int j = 0; j < 4; ++j) hi[j] = (_Float16)0.f;
    } else {
        f16x4 v = *(const f16x4*)(raw + (((size_t)img * H + (hp - 1)) * W + (wp - 1)) * 64 + c4 * 4);
        const float2* st = stats + (img >> 4) * 64 + c4 * 4;
#pragma unroll
        for (int j = 0; j < 4; ++j) {
            float2 s = st[j];
            hi[j] = (_Float16)fmaxf(((float)v[j] - s.x) * s.y, 0.f);
        }
    }
    *(f16x4*)(outF + o) = hi;
}

// pooled fp16 [P][16][H][W][64] + stats + d -> XB padded fp16
__global__ void mix_split(const _Float16* __restrict__ pooled, const float2* __restrict__ stats,
                          const float* __restrict__ d, _Float16* __restrict__ outF,
                          int H, int W, int P, long strideP, int total)
{
    int idx = blockIdx.x * 256 + threadIdx.x;
    if (idx >= total) return;
    const int Hp = H + 2, Wp = W + 2;
    int c4 = idx & 15;
    int t  = idx >> 4;
    int wp = t % Wp; t /= Wp;
    int hp = t % Hp; t /= Hp;
    int n  = t & 15;
    int cc = t >> 4;
    size_t o = (((size_t)(cc * 16 + n) * Hp + hp) * Wp + wp) * 64 + c4 * 4;
    f16x4 hi;
    if (hp == 0 || hp == Hp - 1 || wp == 0 || wp == Wp - 1) {
#pragma unroll
        for (int j = 0; j < 4; ++j) hi[j] = (_Float16)0.f;
    } else {
        float a[4] = {0.f, 0.f, 0.f, 0.f};
        const _Float16* pb = pooled + (((size_t)n * H + (hp - 1)) * W + (wp - 1)) * 64 + c4 * 4;
        for (int p = 0; p < P; ++p) {
            f16x4 v = *(const f16x4*)(pb + (size_t)p * strideP);
            const float2* st = stats + p * 64 + c4 * 4;
            float dc = d[cc * P + p];
#pragma unroll
            for (int j = 0; j < 4; ++j) {
                float2 s = st[j];
                a[j] = fmaf(dc, fmaxf(((float)v[j] - s.x) * s.y, 0.f), a[j]);
            }
        }
#pragma unroll
        for (int j = 0; j < 4; ++j) hi[j] = (_Float16)a[j];
    }
    *(f16x4*)(outF + o) = hi;
}

// L3 mix: pooled fp16 [16][16][7][7][32] -> XB3 fp32 [40][16][7][7][32]
__global__ void mix_last(const _Float16* __restrict__ pooled, const float2* __restrict__ stats,
                         const float* __restrict__ d, float* __restrict__ out, int total)
{
    int idx = blockIdx.x * 256 + threadIdx.x;
    if (idx >= total) return;
    int c  = idx & 31;
    int t  = idx >> 5;
    int hw = t % 49; t /= 49;
    int n  = t & 15;
    int a  = t >> 4;
    float acc = 0.f;
    const _Float16* pb = pooled + ((size_t)n * 49 + hw) * 32 + c;
    for (int p = 0; p < 16; ++p) {
        float2 s = stats[p * 64 + c];
        acc = fmaf(d[a * 16 + p], fmaxf(((float)pb[(size_t)p * 25088] - s.x) * s.y, 0.f), acc);
    }
    out[idx] = acc;
}

// x NCHW [16][3][256][256] -> packed NHWC4 fp16 [16][256][256][4]
__global__ void prep_x(const float* __restrict__ x, _Float16* __restrict__ xF)
{
    int idx = blockIdx.x * 256 + threadIdx.x;   // 16*65536
    if (idx >= 16 * 65536) return;
    int n = idx >> 16, hw = idx & 65535;
    f16x4 hi;
#pragma unroll
    for (int ci = 0; ci < 3; ++ci)
        hi[ci] = (_Float16)x[((size_t)n * 3 + ci) * 65536 + hw];
    hi[3] = (_Float16)0.f;
    *(f16x4*)(xF + (size_t)idx * 4) = hi;
}

// conv1 weights [64][3][7][7] -> fp16 panel [28 kblk][64][8], k=kh*32+kw*4+ci
__global__ void wtrans1(const float* __restrict__ w, _Float16* __restrict__ wt)
{
    int i = blockIdx.x * 256 + threadIdx.x;
    if (i >= 28 * 512) return;
    int j = i & 7, n = (i >> 3) & 63, kb = i >> 9;
    int k = kb * 8 + j;
    int kh = k >> 5, r = k & 31, kw = r >> 2, ci = r & 3;
    float v = (kw < 7 && ci < 3) ? w[((n * 3 + ci) * 7 + kh) * 7 + kw] : 0.f;
    wt[i] = (_Float16)v;
}

// 3x3 weights [P][Cout][64][3][3] -> fp16 panels [p][72 kblk][64][8]
__global__ void wtrans3(const float* __restrict__ w, _Float16* __restrict__ wt,
                        int P, int Cout)
{
    int total = P * 72 * 512;
    for (int i = blockIdx.x * 256 + threadIdx.x; i < total; i += gridDim.x * 256) {
        int j = i & 7, n = (i >> 3) & 63, kb = (i >> 9) % 72, p = (i >> 9) / 72;
        int k = kb * 8 + j;
        int ci = k & 63, tap = k >> 6, kh = tap / 3, kw = tap - 3 * kh;
        float v = (n < Cout) ? w[(((size_t)(p * Cout + n)) * 64 + ci) * 9 + kh * 3 + kw] : 0.f;
        wt[i] = (_Float16)v;
    }
}

// d = softmax_p( log(softmax_p(br*2)) / t ) for all 4 layers
__global__ void dcalc(const float* __restrict__ br0, const float* __restrict__ br1,
                      const float* __restrict__ br2, const float* __restrict__ br3,
                      const void* __restrict__ tptr, float* __restrict__ D)
{
    const int L = blockIdx.x;
    const float* br; int C, P, off;
    if      (L == 0) { br = br0; C = 4;  P = 2;  off = 0;   }
    else if (L == 1) { br = br1; C = 8;  P = 4;  off = 8;   }
    else if (L == 2) { br = br2; C = 16; P = 8;  off = 40;  }
    else             { br = br3; C = 40; P = 16; off = 168; }
    int ti = *(const int*)tptr;
    float t = (ti > 0 && ti < 1000000) ? (float)ti : *(const float*)tptr;
    const int c = threadIdx.x;
    if (c >= C) return;
    float u[16];
    float mx = -1e30f;
#pragma unroll
    for (int p = 0; p < 16; ++p) if (p < P) { u[p] = br[c * P + p] * 2.0f; mx = fmaxf(mx, u[p]); }
    float se = 0.f;
#pragma unroll
    for (int p = 0; p < 16; ++p) if (p < P) se += expf(u[p] - mx);
    float lse = mx + logf(se);
    float mx2 = -1e30f;
#pragma unroll
    for (int p = 0; p < 16; ++p) if (p < P) { u[p] = (u[p] - lse) / t; mx2 = fmaxf(mx2, u[p]); }
    float se2 = 0.f;
#pragma unroll
    for (int p = 0; p < 16; ++p) if (p < P) { u[p] = expf(u[p] - mx2); se2 += u[p]; }
#pragma unroll
    for (int p = 0; p < 16; ++p) if (p < P) D[off + c * P + p] = u[p] / se2;
}

// h1[a,b,i] = relu( sum_f f[a,b,f]*fw1[a,f,i] + fb1[a,i] ); f stored (h,w,c),
// fw1 indexed (c,h,w)
__global__ __launch_bounds__(128) void fc1_k(const float* __restrict__ f,
                                             const float* __restrict__ w1,
                                             const float* __restrict__ b1,
                                             float* __restrict__ h1)
{
    const int a = blockIdx.x >> 4;
    const int b = blockIdx.x & 15;
    const int i = threadIdx.x;
    const float* fv = f + ((size_t)a * 16 + b) * 1568;
    const float* wv = w1 + (size_t)a * 1568 * 128 + i;
    float acc = b1[a * 128 + i];
    for (int hw = 0; hw < 49; ++hw)
        for (int c = 0; c < 32; ++c)
            acc = fmaf(fv[hw * 32 + c], wv[(size_t)(c * 49 + hw) * 128], acc);
    h1[((size_t)a * 16 + b) * 128 + i] = fmaxf(acc, 0.f);
}

__global__ __launch_bounds__(128) void fc23_k(const float* __restrict__ h1,
                                              const float* __restrict__ w2,
                                              const float* __restrict__ b2,
                                              const float* __restrict__ w3,
                                              const float* __restrict__ b3,
                                              float* __restrict__ out)
{
    __shared__ float sh1[16][128];
    __shared__ float sh2[16][128];
    const int a = blockIdx.x;
    const int i = threadIdx.x;
    for (int b = 0; b < 16; ++b) sh1[b][i] = h1[((size_t)a * 16 + b) * 128 + i];
    __syncthreads();
    float acc[16];
#pragma unroll
    for (int b = 0; b < 16; ++b) acc[b] = b2[a * 128 + i];
    for (int ff = 0; ff < 128; ++ff) {
        float wv = w2[((size_t)a * 128 + ff) * 128 + i];
#pragma unroll
        for (int b = 0; b < 16; ++b) acc[b] = fmaf(sh1[b][ff], wv, acc[b]);
    }
    for (int b = 0; b < 16; ++b) sh2[b][i] = fmaxf(acc[b], 0.f);
    __syncthreads();
    if (i < 16) {
        float o = b3[a];
        for (int ff = 0; ff < 128; ++ff) o = fmaf(sh2[i][ff], w3[a * 128 + ff], o);
        out[i * 40 + a] = o;
    }
}

extern "C" void kernel_launch(void* const* d_in, const int* in_sizes, int n_in,
                              void* d_out, int out_size, void* d_ws, size_t ws_size,
                              hipStream_t stream)
{
    (void)in_sizes; (void)n_in;

    const float* x   = (const float*)d_in[0];
    const float* w10 = (const float*)d_in[1];
    const float* wa[4] = {(const float*)d_in[3],  (const float*)d_in[7],
                          (const float*)d_in[11], (const float*)d_in[15]};
    const float* wb[4] = {(const float*)d_in[5],  (const float*)d_in[9],
                          (const float*)d_in[13], (const float*)d_in[17]};
    const float* br[4] = {(const float*)d_in[19], (const float*)d_in[20],
                          (const float*)d_in[21], (const float*)d_in[22]};
    const float* fw1 = (const float*)d_in[23];
    const float* fb1 = (const float*)d_in[24];
    const float* fw2 = (const float*)d_in[25];
    const float* fb2 = (const float*)d_in[26];
    const float* fw3 = (const float*)d_in[27];
    const float* fb3 = (const float*)d_in[28];
    float* out = (float*)d_out;

    const int Pl[4]  = {2, 4, 8, 16};
    const int CBs[4] = {64, 64, 64, 32};

    // ---- workspace arenas (f32 units); total ~47.0M f32 = 188 MB ----
    const size_t NEED = 47000000ull * 4ull;
    if (ws_size < NEED) {
        hipMemsetAsync(d_out, 0, (size_t)out_size * sizeof(float), stream);
        return;
    }
    float* ws = (float*)d_ws;
    size_t o = 0;
    _Float16* WT1 = (_Float16*)(ws + o); o += 7168;
    _Float16 *WTA[4], *WTB[4];
    for (int L = 0; L < 4; ++L) {
        WTA[L] = (_Float16*)(ws + o); o += (size_t)Pl[L] * 18432;
        WTB[L] = (_Float16*)(ws + o); o += (size_t)Pl[L] * 18432;
    }
    float*  D     = ws + o; o += 1024;
    float2* STATS = (float2*)(ws + o); o += 4352;
    float2* STATS_C1 = STATS;
    float2* STATS_A  = STATS + 64;     // up to 128 entries (z-batched L0)
    float2* STATS_B  = STATS + 1088;
    float*  H1 = ws + o; o += 81920;
    float*  A6 = ws + o; o += 524288;      // conv partials (128 x 2048 float2 max)
    float*  A5 = ws + o; o += 4000000;     // pooled fp16 / conv1 partials
    float*  A4 = ws + o; o += 16000000;    // raw conv outputs fp16 NHWC
    float*  A3 = ws + o; o += 16600000;    // fp16 split buf / xc
    float*  A2 = ws + o; o += 8400000;     // fp16 Y / XB chain / XB3 fp32

    float2* PART   = (float2*)A6;
    float2* PARTC1 = (float2*)A5;          // conv1: 64x7813 float2 fits 4M f32
    _Float16* xcF = (_Float16*)A3;
    _Float16* A2F = (_Float16*)A2;
    _Float16* A3F = (_Float16*)A3;
    _Float16* A4F = (_Float16*)A4;
    _Float16* A5F = (_Float16*)A5;

    // ---- weights + mix coefficients + conv1 input prep ----
    prep_x<<<4096, 256, 0, stream>>>(x, xcF);
    wtrans1<<<56, 256, 0, stream>>>(w10, WT1);
    for (int L = 0; L < 4; ++L) {
        int tA = Pl[L] * 72 * 512;
        wtrans3<<<DIVUP(tA, 256), 256, 0, stream>>>(wa[L], WTA[L], Pl[L], 64);
        wtrans3<<<DIVUP(tA, 256), 256, 0, stream>>>(wb[L], WTB[L], Pl[L], CBs[L]);
    }
    dcalc<<<4, 64, 0, stream>>>(br[0], br[1], br[2], br[3], d_in[29], D);

    // ---- conv1: xc -> pooled raw fp16 A4 [16,125,125,64] + stats ----
    conv_mfma<1, 1, 256, 256, 250, 250, 64, 1000000, 7, 125, 125, 125, 125>
        <<<dim3(7813, 1, 1), 256, 0, stream>>>(xcF, 0, WT1, A4F, 0, PARTC1);
    bn_finalize<<<64, 256, 0, stream>>>(PARTC1, 7813, 1.0 / 1000000.0, STATS_C1);
    bn_split<<<DIVUP(16 * 127 * 127 * 16, 256), 256, 0, stream>>>(
        A4F, STATS_C1, A2F, 125, 125, 16 * 127 * 127 * 16);

    // ---- layer 0: both parents z-batched; conv-a 2D-tiled (Ht=32,Wt=4 -> 2048) --
    conv_mfma<0, 0, 127, 127, 125, 125, 64, 250000, 18, 0, 0, 1, 1>
        <<<dim3(2048, 1, 2), 256, 0, stream>>>(
            A2F, 0, WTA[0], A4F, 16000000, PART);
    bn_finalize<<<128, 256, 0, stream>>>(PART, 2048, 1.0 / 250000.0, STATS_A);
    bn_split<<<DIVUP(2 * 16 * 127 * 127 * 16, 256), 256, 0, stream>>>(
        A4F, STATS_A, A3F, 125, 125, 2 * 16 * 127 * 127 * 16);
    conv_mfma<1, 0, 127, 127, 125, 125, 64, 254016, 18, 62, 62, 63, 63>
        <<<dim3(1985, 1, 2), 256, 0, stream>>>(
            A3F, 16516096, WTB[0], A5F, 3936256, PART);
    bn_finalize<<<128, 256, 0, stream>>>(PART, 1985, 1.0 / 250000.0, STATS_B);
    mix_split<<<DIVUP(4 * 16 * 64 * 64 * 16, 256), 256, 0, stream>>>(
        A5F, STATS_B, D + 0, A2F, 62, 62, 2, 3936256, 4 * 16 * 64 * 64 * 16);

    // ---- layer 1 (z=4); conv-a 2D-tiled (Ht=16,Wt=2 -> 512) ----
    conv_mfma<0, 0, 64, 64, 62, 62, 64, 61504, 18, 0, 0, 1, 1>
        <<<dim3(512, 1, 4), 256, 0, stream>>>(
            A2F, 4194304, WTA[1], A4F, 3936256, PART);
    bn_finalize<<<256, 256, 0, stream>>>(PART, 512, 1.0 / 61504.0, STATS_A);
    bn_split<<<DIVUP(64 * 64 * 64 * 16, 256), 256, 0, stream>>>(
        A4F, STATS_A, A3F, 62, 62, 64 * 64 * 64 * 16);
    conv_mfma<1, 0, 64, 64, 62, 62, 64, 61504, 18, 31, 31, 31, 31>
        <<<dim3(481, 1, 4), 256, 0, stream>>>(
            A3F, 4194304, WTB[1], A5F, 984064, PART);
    bn_finalize<<<256, 256, 0, stream>>>(PART, 481, 1.0 / 61504.0, STATS_B);
    mix_split<<<DIVUP(8 * 16 * 33 * 33 * 16, 256), 256, 0, stream>>>(
        A5F, STATS_B, D + 8, A2F, 31, 31, 4, 984064, 8 * 16 * 33 * 33 * 16);

    // ---- layer 2 (z=8); conv-a 2D-tiled (Ht=8,Wt=1 -> 128) ----
    conv_mfma<0, 0, 33, 33, 31, 31, 64, 15376, 18, 0, 0, 1, 1>
        <<<dim3(128, 1, 8), 256, 0, stream>>>(
            A2F, 1115136, WTA[2], A4F, 984064, PART);
    bn_finalize<<<512, 256, 0, stream>>>(PART, 128, 1.0 / 15376.0, STATS_A);
    bn_split<<<DIVUP(128 * 33 * 33 * 16, 256), 256, 0, stream>>>(
        A4F, STATS_A, A3F, 31, 31, 128 * 33 * 33 * 16);
    conv_mfma<1, 0, 33, 33, 31, 31, 64, 16384, 18, 15, 15, 16, 16>
        <<<dim3(128, 1, 8), 256, 0, stream>>>(
            A3F, 1115136, WTB[2], A5F, 230400, PART);
    bn_finalize<<<512, 256, 0, stream>>>(PART, 128, 1.0 / 15376.0, STATS_B);
    mix_split<<<DIVUP(16 * 16 * 17 * 17 * 16, 256), 256, 0, stream>>>(
        A5F, STATS_B, D + 40, A2F, 15, 15, 8, 230400, 16 * 16 * 17 * 17 * 16);

    // ---- layer 3 (z=16); conv-a 2D-tiled (Ht=4,Wt=1 -> 64) ----
    conv_mfma<0, 0, 17, 17, 15, 15, 64, 3600, 18, 0, 0, 1, 1>
        <<<dim3(64, 1, 16), 256, 0, stream>>>(
            A2F, 295936, WTA[3], A4F, 230400, PART);
    bn_finalize<<<1024, 256, 0, stream>>>(PART, 64, 1.0 / 3600.0, STATS_A);
    bn_split<<<DIVUP(256 * 17 * 17 * 16, 256), 256, 0, stream>>>(
        A4F, STATS_A, A3F, 15, 15, 256 * 17 * 17 * 16);
    conv_mfma<1, 0, 17, 17, 15, 15, 32, 4096, 18, 7, 7, 8, 8>
        <<<dim3(32, 1, 16), 256, 0, stream>>>(
            A3F, 295936, WTB[3], A5F, 25088, PART);
    bn_finalize<<<1024, 256, 0, stream>>>(PART, 32, 1.0 / 3600.0, STATS_B);
    mix_last<<<DIVUP(40 * 16 * 49 * 32, 256), 256, 0, stream>>>(
        A5F, STATS_B, D + 168, A2, 40 * 16 * 49 * 32);

    // ---- FC heads ----
    fc1_k<<<640, 128, 0, stream>>>(A2, fw1, fb1, H1);
    fc23_k<<<40, 128, 0, stream>>>(H1, fw2, fb2, fw3, fb3, out);
}